// Round 1
// baseline (12996.704 us; speedup 1.0000x reference)
//
#include <hip/hip_runtime.h>
#include <math.h>

// ---------------------------------------------------------------------------
// RPN GMM head, MI355X. Round 1: correct fp32 implementation.
// Key transform: conv3x3(concat[x, onehot_n], w_rpn) ==
//   conv3x3(x, w_rpn[:, :256]) + edge_bias_n(y_case, x_case)
// so the 4 per-component 260ch convs collapse to ONE shared 256ch conv plus
// a 3x3x4x256 bias table (partial tap sums of w_rpn[:, 256+n]).
// ---------------------------------------------------------------------------

#define OCT 128   // output channels per block
#define PTY 16    // tile rows
#define PTX 8     // tile cols
#define ICC 8     // input-channel chunk staged in LDS

// ------------------- big 3x3 conv: 256 -> 256 (optional relu) --------------
// grid: (tilesX*tilesY, 256/OCT, B), block 256.
// per-thread: 8 oc x 8 x-positions (one row). LDS: weights [72][128] + input
// tile [8][18][12]. Weight staging is coalesced along K (72 contiguous floats
// per oc per chunk) and stores are bank-conflict-free (consecutive oc).
__global__ __launch_bounds__(256) void conv3x3_big(
    const float* __restrict__ in,   // [B,256,H,W]
    const float* __restrict__ w,    // [256, wic, 3,3], wicstride = wic*9
    const float* __restrict__ bias, // [256]
    float* __restrict__ out,        // [B,256,H,W]
    int H, int W, int tilesX, int wicstride, int relu)
{
    __shared__ float s_w[72][OCT];            // 36,864 B
    __shared__ float s_in[ICC][PTY+2][PTX+4]; //  6,912 B

    const int tid = threadIdx.x;
    const int ty = blockIdx.x / tilesX, tx = blockIdx.x % tilesX;
    const int y0 = ty * PTY, x0 = tx * PTX;
    const int oc0 = blockIdx.y * OCT;
    const int b   = blockIdx.z;
    const size_t HW = (size_t)H * W;

    const int oc_g = tid & 15;   // 16 oc groups of 8
    const int py   = tid >> 4;   // 16 rows
    const int oc_t = oc_g * 8;

    float acc[8][8];
#pragma unroll
    for (int i = 0; i < 8; ++i)
#pragma unroll
        for (int j = 0; j < 8; ++j) acc[i][j] = 0.f;

    const int oc_l = tid & 127;  // weight-staging oc
    const int half = tid >> 7;   // 0/1 -> k range 0..35 / 36..71

    const size_t inB = (size_t)b * 256 * HW;

#pragma unroll 1
    for (int ic0 = 0; ic0 < 256; ic0 += ICC) {
        __syncthreads();
        // ---- stage input tile (with halo, zero-filled OOB) ----
        for (int idx = tid; idx < ICC*(PTY+2)*(PTX+2); idx += 256) {
            int ic = idx / ((PTY+2)*(PTX+2));
            int r  = idx % ((PTY+2)*(PTX+2));
            int yy = r / (PTX+2);
            int xx = r % (PTX+2);
            int yi = y0 - 1 + yy;
            int xi = x0 - 1 + xx;
            float v = 0.f;
            if (yi >= 0 && yi < H && xi >= 0 && xi < W)
                v = in[inB + ((size_t)(ic0+ic))*HW + (size_t)yi*W + xi];
            s_in[ic][yy][xx] = v;
        }
        // ---- stage weights: 128 oc x 72 k (ic chunk contiguous in memory) ----
        {
            const float* wp = w + (size_t)(oc0 + oc_l) * wicstride + ic0*9 + half*36;
            float4 v4[9];
#pragma unroll
            for (int j = 0; j < 9; ++j) v4[j] = ((const float4*)wp)[j];
#pragma unroll
            for (int j = 0; j < 9; ++j) {
                int k = half*36 + j*4;
                s_w[k+0][oc_l] = v4[j].x;
                s_w[k+1][oc_l] = v4[j].y;
                s_w[k+2][oc_l] = v4[j].z;
                s_w[k+3][oc_l] = v4[j].w;
            }
        }
        __syncthreads();

        // ---- compute ----
#pragma unroll 1
        for (int ic = 0; ic < ICC; ++ic) {
#pragma unroll
            for (int ky = 0; ky < 3; ++ky) {
                float r[10];
                const float* rp = &s_in[ic][py+ky][0];
#pragma unroll
                for (int j = 0; j < 10; ++j) r[j] = rp[j];
#pragma unroll
                for (int kx = 0; kx < 3; ++kx) {
                    const float* wpt = &s_w[ic*9 + ky*3 + kx][oc_t];
                    float wv[8];
#pragma unroll
                    for (int i = 0; i < 8; ++i) wv[i] = wpt[i];
#pragma unroll
                    for (int i = 0; i < 8; ++i)
#pragma unroll
                        for (int j = 0; j < 8; ++j)
                            acc[i][j] = fmaf(wv[i], r[j+kx], acc[i][j]);
                }
            }
        }
    }

    // ---- epilogue ----
    const int y = y0 + py;
    if (y < H) {
#pragma unroll
        for (int i = 0; i < 8; ++i) {
            const int oc = oc0 + oc_t + i;
            const float bv = bias[oc];
            float* op = out + inB + (size_t)oc*HW + (size_t)y*W;
#pragma unroll
            for (int j = 0; j < 8; ++j) {
                int x = x0 + j;
                if (x < W) {
                    float v = acc[i][j] + bv;
                    if (relu) v = fmaxf(v, 0.f);
                    op[x] = v;
                }
            }
        }
    }
}

// ---------------- qy conv (256->4, 3x3) fused with softmax -> mix ----------
__global__ __launch_bounds__(256) void qy_softmax_kernel(
    const float* __restrict__ h2, const float* __restrict__ wqy,
    const float* __restrict__ bqy, float* __restrict__ mix,
    int H, int W)
{
    const int pos = blockIdx.x*256 + threadIdx.x;
    const int b = blockIdx.z;
    const int HW = H*W;
    if (pos >= HW) return;
    const int y = pos / W, x = pos % W;

    int   offt[9];
    float mskt[9];
#pragma unroll
    for (int ky = 0; ky < 3; ++ky)
#pragma unroll
        for (int kx = 0; kx < 3; ++kx) {
            int t = ky*3 + kx;
            int yi = y + ky - 1, xi = x + kx - 1;
            bool v = (yi >= 0 && yi < H && xi >= 0 && xi < W);
            offt[t] = v ? yi*W + xi : 0;
            mskt[t] = v ? 1.f : 0.f;
        }

    float a0 = bqy[0], a1 = bqy[1], a2 = bqy[2], a3 = bqy[3];
    const float* inb = h2 + (size_t)b * 256 * HW;
    for (int ic = 0; ic < 256; ++ic) {
        const float* ip = inb + (size_t)ic * HW;
        const float* wp = wqy + ic*9;
#pragma unroll
        for (int t = 0; t < 9; ++t) {
            float v = ip[offt[t]] * mskt[t];
            a0 = fmaf(wp[t         ], v, a0);
            a1 = fmaf(wp[t + 2304  ], v, a1);   // (1*256)*9
            a2 = fmaf(wp[t + 4608  ], v, a2);
            a3 = fmaf(wp[t + 6912  ], v, a3);
        }
    }
    float mx = fmaxf(fmaxf(a0,a1), fmaxf(a2,a3));
    float e0 = expf(a0-mx), e1 = expf(a1-mx), e2 = expf(a2-mx), e3 = expf(a3-mx);
    float s = 1.f / (e0+e1+e2+e3);
    float* mp = mix + (size_t)b*4*HW + pos;
    mp[0]      = e0*s;
    mp[HW]     = e1*s;
    mp[2*(size_t)HW] = e2*s;
    mp[3*(size_t)HW] = e3*s;
}

// ------------- edge-bias table: btab[cy][cx][n][oc], 3*3*4*256 -------------
__global__ void bias_table_kernel(const float* __restrict__ w_rpn,
                                  float* __restrict__ btab)
{
    const int oc = threadIdx.x;  // 256 threads
    for (int cy = 0; cy < 3; ++cy)
        for (int cx = 0; cx < 3; ++cx)
            for (int n = 0; n < 4; ++n) {
                float s = 0.f;
                for (int ky = 0; ky < 3; ++ky) {
                    if (cy == 0 && ky == 0) continue;  // y==0: top row invalid
                    if (cy == 2 && ky == 2) continue;  // y==H-1
                    for (int kx = 0; kx < 3; ++kx) {
                        if (cx == 0 && kx == 0) continue;
                        if (cx == 2 && kx == 2) continue;
                        s += w_rpn[(size_t)oc*2340 + (256+n)*9 + ky*3 + kx];
                    }
                }
                btab[((cy*3 + cx)*4 + n)*256 + oc] = s;
            }
}

// ------ epilogue: per-component relu+1x1 heads, mixture, decode, clip ------
__global__ __launch_bounds__(256) void final_kernel(
    const float* __restrict__ mix, const float* __restrict__ U,
    const float* __restrict__ btab,
    const float* __restrict__ w_cls, const float* __restrict__ b_cls,
    const float* __restrict__ w_mean, const float* __restrict__ b_mean,
    const float* __restrict__ im_info,
    float* __restrict__ out,
    int H, int W, int out_base, int TOT, float stride_)
{
    const int pos = blockIdx.x*256 + threadIdx.x;
    const int b = blockIdx.z;
    const int HW = H*W;
    if (pos >= HW) return;
    const int y = pos / W, x = pos % W;
    const int cy = (y == 0) ? 0 : ((y == H-1) ? 2 : 1);
    const int cx = (x == 0) ? 0 : ((x == W-1) ? 2 : 1);
    const float* bp = btab + (size_t)((cy*3 + cx)*4) * 256;

    float sA[4] = {0,0,0,0}, sB[4] = {0,0,0,0};
    float d0[4] = {0,0,0,0}, d1[4] = {0,0,0,0};
    float d2[4] = {0,0,0,0}, d3[4] = {0,0,0,0};

    const float* up = U + (size_t)b*256*HW + pos;
    for (int oc = 0; oc < 256; ++oc) {
        float u  = up[(size_t)oc*HW];
        float wc0 = w_cls[oc],       wc1 = w_cls[256+oc];
        float wm0 = w_mean[oc],      wm1 = w_mean[256+oc];
        float wm2 = w_mean[512+oc],  wm3 = w_mean[768+oc];
#pragma unroll
        for (int n = 0; n < 4; ++n) {
            float t = fmaxf(u + bp[n*256 + oc], 0.f);
            sA[n] = fmaf(wc0, t, sA[n]);
            sB[n] = fmaf(wc1, t, sB[n]);
            d0[n] = fmaf(wm0, t, d0[n]);
            d1[n] = fmaf(wm1, t, d1[n]);
            d2[n] = fmaf(wm2, t, d2[n]);
            d3[n] = fmaf(wm3, t, d3[n]);
        }
    }

    const float* mp = mix + (size_t)b*4*HW + pos;
    float mm[4] = { mp[0], mp[HW], mp[2*(size_t)HW], mp[3*(size_t)HW] };
    float sc0 = b_cls[0], sc1 = b_cls[1];
    float D0 = b_mean[0], D1 = b_mean[1], D2 = b_mean[2], D3 = b_mean[3];
#pragma unroll
    for (int n = 0; n < 4; ++n) {
        sc0 += mm[n]*sA[n];  sc1 += mm[n]*sB[n];
        D0  += mm[n]*d0[n];  D1  += mm[n]*d1[n];
        D2  += mm[n]*d2[n];  D3  += mm[n]*d3[n];
    }

    // decode (anchor is a square of side stride*8 centered at (x+.5, y+.5)*stride)
    const float aw  = stride_ * 8.f;
    const float acx = (x + 0.5f) * stride_;
    const float acy = (y + 0.5f) * stride_;
    const float cxx = acx + D0 * aw;
    const float cyy = acy + D1 * aw;
    const float e2 = fminf(fmaxf(D2, -10.f), 10.f);
    const float e3 = fminf(fmaxf(D3, -10.f), 10.f);
    const float bw = aw * expf(e2);
    const float bh = aw * expf(e3);
    const float imH = im_info[b*6 + 0], imW = im_info[b*6 + 1];
    const float x1 = fminf(fmaxf(cxx - 0.5f*bw, 0.f), imW);
    const float y1 = fminf(fmaxf(cyy - 0.5f*bh, 0.f), imH);
    const float x2 = fminf(fmaxf(cxx + 0.5f*bw, 0.f), imW);
    const float y2 = fminf(fmaxf(cyy + 0.5f*bh, 0.f), imH);

    float* op = out + ((size_t)b*TOT + out_base + pos) * 6;
    op[0] = x1; op[1] = y1; op[2] = x2; op[3] = y2; op[4] = sc0; op[5] = sc1;
}

// ---------------------------------------------------------------------------
extern "C" void kernel_launch(void* const* d_in, const int* in_sizes, int n_in,
                              void* d_out, int out_size, void* d_ws, size_t ws_size,
                              hipStream_t stream)
{
    (void)in_sizes; (void)n_in; (void)out_size; (void)ws_size;

    const float* feats[5] = { (const float*)d_in[0], (const float*)d_in[1],
                              (const float*)d_in[2], (const float*)d_in[3],
                              (const float*)d_in[4] };
    const float* im_info = (const float*)d_in[5];
    const float* w_qy1 = (const float*)d_in[6];
    const float* b_qy1 = (const float*)d_in[7];
    const float* w_qy2 = (const float*)d_in[8];
    const float* b_qy2 = (const float*)d_in[9];
    const float* w_qy  = (const float*)d_in[10];
    const float* b_qy  = (const float*)d_in[11];
    const float* w_rpn = (const float*)d_in[12];
    const float* b_rpn = (const float*)d_in[13];
    const float* w_cls = (const float*)d_in[14];
    const float* b_cls = (const float*)d_in[15];
    const float* w_mean= (const float*)d_in[16];
    const float* b_mean= (const float*)d_in[17];
    float* out = (float*)d_out;

    // workspace layout (floats): 2 big ping-pong buffers + mix + bias table
    const size_t BIG = (size_t)2 * 256 * 200 * 304;  // 31,129,600 floats
    float* ws  = (float*)d_ws;
    float* A   = ws;                 // h1 / reused
    float* Bb  = ws + BIG;           // h2, then rpn-shared U
    float* MIX = ws + 2*BIG;         // [B,4,H,W] softmax weights
    float* btab= MIX + (size_t)2*4*200*304;

    bias_table_kernel<<<1, 256, 0, stream>>>(w_rpn, btab);

    const int   Hs[5] = {13, 25, 50, 100, 200};
    const int   Ws5[5]= {19, 38, 76, 152, 304};
    const float st[5] = {64.f, 32.f, 16.f, 8.f, 4.f};
    const int TOT = 80997;

    int base = 0;
    for (int L = 0; L < 5; ++L) {
        const int H = Hs[L], W = Ws5[L], HW = H*W;
        const int tilesX = (W + PTX - 1) / PTX;
        const int tilesY = (H + PTY - 1) / PTY;
        dim3 gconv(tilesX * tilesY, 256/OCT, 2);
        dim3 gpos((HW + 255)/256, 1, 2);

        // h1 = relu(conv(x, w_qy1))
        conv3x3_big<<<gconv, 256, 0, stream>>>(feats[L], w_qy1, b_qy1, A,
                                               H, W, tilesX, 256*9, 1);
        // h2 = relu(conv(h1, w_qy2))
        conv3x3_big<<<gconv, 256, 0, stream>>>(A, w_qy2, b_qy2, Bb,
                                               H, W, tilesX, 256*9, 1);
        // mix = softmax(conv(h2, w_qy) + b_qy)
        qy_softmax_kernel<<<gpos, 256, 0, stream>>>(Bb, w_qy, b_qy, MIX, H, W);
        // U = conv(x, w_rpn[:, :256]) + b_rpn   (shared across components)
        conv3x3_big<<<gconv, 256, 0, stream>>>(feats[L], w_rpn, b_rpn, Bb,
                                               H, W, tilesX, 260*9, 0);
        // heads + mixture + decode + clip
        final_kernel<<<gpos, 256, 0, stream>>>(MIX, Bb, btab, w_cls, b_cls,
                                               w_mean, b_mean, im_info, out,
                                               H, W, base, TOT, st[L]);
        base += HW;
    }
}

// Round 2
// 4208.880 us; speedup vs baseline: 3.0879x; 3.0879x over previous
//
#include <hip/hip_runtime.h>
#include <math.h>

// ---------------------------------------------------------------------------
// RPN GMM head, MI355X. Round 2: bf16 MFMA implicit-GEMM conv.
// conv3x3(concat[x, onehot_n], w_rpn) == conv3x3(x, w_rpn[:,:256]) + edge bias
// so 4 component convs collapse to ONE shared conv + 3x3x4x256 bias table.
// Conv = 9 tap-GEMMs, 128oc x 128pos tile, mfma_f32_16x16x32_bf16.
// LDS holds the input tile TRANSPOSED (ic contiguous, x-stride padded to 72
// bf16) so B-fragments are aligned ds_read_b128 with ~2-way (free) aliasing.
// A-fragments come straight from L2 (packed [tap][oc][ic] bf16 weights).
// ---------------------------------------------------------------------------

typedef __attribute__((ext_vector_type(8))) short short8;
typedef __attribute__((ext_vector_type(4))) float f32x4;

static __device__ __forceinline__ ushort f2bf(float f) {
    union { float f; unsigned u; } x; x.f = f;
    unsigned r = (x.u + 0x7FFFu + ((x.u >> 16) & 1u)) >> 16;  // RNE
    return (ushort)r;
}
static __device__ __forceinline__ float bf2f(ushort u) {
    union { unsigned u; float f; } x; x.u = ((unsigned)u) << 16;
    return x.f;
}

// ---------------- fp32 -> bf16 feature conversion (vectorized) -------------
__global__ __launch_bounds__(256) void cvt_bf16_kernel(
    const float* __restrict__ src, ushort* __restrict__ dst, int n4)
{
    int i = blockIdx.x * 256 + threadIdx.x;
    if (i >= n4) return;
    const float4 v = ((const float4*)src)[i];
    ushort4 o;
    o.x = f2bf(v.x); o.y = f2bf(v.y); o.z = f2bf(v.z); o.w = f2bf(v.w);
    ((ushort4*)dst)[i] = o;
}

// -------- weight pack: w[oc][ic][ky][kx] fp32 -> pw[tap][oc][ic] bf16 ------
__global__ __launch_bounds__(256) void pack_w_kernel(
    const float* __restrict__ w, ushort* __restrict__ pw, int icfull)
{
    int idx = blockIdx.x * 256 + threadIdx.x;   // 9*256*256 = 589824
    if (idx >= 589824) return;
    int ic  = idx & 255;
    int oc  = (idx >> 8) & 255;
    int tap = idx >> 16;
    pw[idx] = f2bf(w[((size_t)oc * icfull + ic) * 9 + tap]);
}

// ------------------- big 3x3 conv: 256 -> 256, bf16 MFMA -------------------
// grid: (tilesX*tilesY, 2, B), block 256 = 4 waves.
// Tile: 128 oc x (16 x-cols x 8 y-rows) positions. Wave w: oc-half (w>>1),
// pos-row-quad (w&1). Each wave: 4x4 mfma tiles of 16oc x 16pos, acc 64 VGPR.
__global__ __launch_bounds__(256) void conv3x3_mfma(
    const ushort* __restrict__ in,   // [B,256,H,W] bf16
    const ushort* __restrict__ pw,   // [9][256][256] bf16 packed weights
    const float*  __restrict__ bias, // [256]
    ushort* __restrict__ out,        // [B,256,H,W] bf16
    int H, int W, int tilesX, int relu)
{
    __shared__ __align__(16) ushort s_in[10 * 18 * 72];  // 25,920 B

    const int tid  = threadIdx.x;
    const int lane = tid & 63;
    const int wave = tid >> 6;
    const int lm   = lane & 15;
    const int quad = lane >> 4;
    const int wrow = wave >> 1;   // oc half
    const int wcol = wave & 1;    // pos row quad

    const int y0  = (blockIdx.x / tilesX) * 8;
    const int x0  = (blockIdx.x % tilesX) * 16;
    const int oc0 = blockIdx.y * 128;
    const int b   = blockIdx.z;
    const size_t HW  = (size_t)H * W;
    const size_t inB = (size_t)b * 256 * HW;

    f32x4 acc[4][4];
#pragma unroll
    for (int i = 0; i < 4; ++i)
#pragma unroll
        for (int j = 0; j < 4; ++j) acc[i][j] = (f32x4){0.f, 0.f, 0.f, 0.f};

    // per-lane fragment bases
    const ushort* pwl = pw + (size_t)(oc0 + wrow * 64 + lm) * 256 + quad * 8;
    const int sbase = (wcol * 4 * 18 + lm) * 72 + quad * 8;

#pragma unroll 1
    for (int ic0 = 0; ic0 < 256; ic0 += 64) {
        __syncthreads();
        // stage transposed: s_in[row][x][ic], rows y0-1..y0+8, x x0-1..x0+16
        for (int site = tid; site < 640; site += 256) {
            const int ic = site & 63;
            const int r  = site >> 6;
            const int yi = y0 - 1 + r;
            const bool rowok = (yi >= 0) && (yi < H);
            const ushort* gp = in + inB + (size_t)(ic0 + ic) * HW
                             + (size_t)(rowok ? yi : 0) * W;
            ushort* sp = &s_in[r * 18 * 72 + ic];
#pragma unroll
            for (int xx = 0; xx < 18; ++xx) {
                const int xi = x0 - 1 + xx;
                ushort v = 0;
                if (rowok && xi >= 0 && xi < W) v = gp[xi];
                sp[xx * 72] = v;
            }
        }
        __syncthreads();

#pragma unroll
        for (int tap = 0; tap < 9; ++tap) {
            const int ky = tap / 3, kx = tap % 3;
            const ushort* pa = pwl + tap * 65536 + ic0;
#pragma unroll
            for (int sub = 0; sub < 2; ++sub) {
                short8 av[4], bv[4];
#pragma unroll
                for (int i = 0; i < 4; ++i)
                    av[i] = *(const short8*)(pa + i * 4096 + sub * 32);
#pragma unroll
                for (int j = 0; j < 4; ++j)
                    bv[j] = *(const short8*)&s_in[sbase + ((j + ky) * 18 + kx) * 72 + sub * 32];
#pragma unroll
                for (int i = 0; i < 4; ++i)
#pragma unroll
                    for (int j = 0; j < 4; ++j)
                        acc[i][j] = __builtin_amdgcn_mfma_f32_16x16x32_bf16(
                            av[i], bv[j], acc[i][j], 0, 0, 0);
            }
        }
    }

    // epilogue: D layout col=lane&15 (pos x), row=quad*4+reg (oc within 16)
    const int x = x0 + lm;
    if (x < W) {
#pragma unroll
        for (int i = 0; i < 4; ++i) {
            const int ocb = oc0 + wrow * 64 + i * 16 + quad * 4;
            const float4 bv4 = *(const float4*)(bias + ocb);
            const float barr[4] = {bv4.x, bv4.y, bv4.z, bv4.w};
#pragma unroll
            for (int j = 0; j < 4; ++j) {
                const int y = y0 + wcol * 4 + j;
                if (y < H) {
#pragma unroll
                    for (int reg = 0; reg < 4; ++reg) {
                        float v = acc[i][j][reg] + barr[reg];
                        if (relu) v = fmaxf(v, 0.f);
                        out[inB + (size_t)(ocb + reg) * HW + (size_t)y * W + x] = f2bf(v);
                    }
                }
            }
        }
    }
}

// ---------------- qy conv (256->4, 3x3) fused with softmax -> mix ----------
__global__ __launch_bounds__(256) void qy_softmax_kernel(
    const ushort* __restrict__ h2, const float* __restrict__ wqy,
    const float* __restrict__ bqy, float* __restrict__ mix,
    int H, int W)
{
    const int pos = blockIdx.x * 256 + threadIdx.x;
    const int b = blockIdx.z;
    const int HW = H * W;
    if (pos >= HW) return;
    const int y = pos / W, x = pos % W;

    int   offt[9];
    float mskt[9];
#pragma unroll
    for (int ky = 0; ky < 3; ++ky)
#pragma unroll
        for (int kx = 0; kx < 3; ++kx) {
            int t = ky * 3 + kx;
            int yi = y + ky - 1, xi = x + kx - 1;
            bool v = (yi >= 0 && yi < H && xi >= 0 && xi < W);
            offt[t] = v ? yi * W + xi : 0;
            mskt[t] = v ? 1.f : 0.f;
        }

    float a0 = bqy[0], a1 = bqy[1], a2 = bqy[2], a3 = bqy[3];
    const ushort* inb = h2 + (size_t)b * 256 * HW;
    for (int ic = 0; ic < 256; ++ic) {
        const ushort* ip = inb + (size_t)ic * HW;
        const float* wp = wqy + ic * 9;
#pragma unroll
        for (int t = 0; t < 9; ++t) {
            float v = bf2f(ip[offt[t]]) * mskt[t];
            a0 = fmaf(wp[t       ], v, a0);
            a1 = fmaf(wp[t + 2304], v, a1);
            a2 = fmaf(wp[t + 4608], v, a2);
            a3 = fmaf(wp[t + 6912], v, a3);
        }
    }
    float mx = fmaxf(fmaxf(a0, a1), fmaxf(a2, a3));
    float e0 = expf(a0 - mx), e1 = expf(a1 - mx);
    float e2 = expf(a2 - mx), e3 = expf(a3 - mx);
    float s = 1.f / (e0 + e1 + e2 + e3);
    float* mp = mix + (size_t)b * 4 * HW + pos;
    mp[0]            = e0 * s;
    mp[HW]           = e1 * s;
    mp[2*(size_t)HW] = e2 * s;
    mp[3*(size_t)HW] = e3 * s;
}

// ------------- edge-bias table: btab[cy][cx][n][oc], 3*3*4*256 -------------
__global__ void bias_table_kernel(const float* __restrict__ w_rpn,
                                  float* __restrict__ btab)
{
    const int oc = threadIdx.x;  // 256 threads
    for (int cy = 0; cy < 3; ++cy)
        for (int cx = 0; cx < 3; ++cx)
            for (int n = 0; n < 4; ++n) {
                float s = 0.f;
                for (int ky = 0; ky < 3; ++ky) {
                    if (cy == 0 && ky == 0) continue;
                    if (cy == 2 && ky == 2) continue;
                    for (int kx = 0; kx < 3; ++kx) {
                        if (cx == 0 && kx == 0) continue;
                        if (cx == 2 && kx == 2) continue;
                        s += w_rpn[(size_t)oc * 2340 + (256 + n) * 9 + ky * 3 + kx];
                    }
                }
                btab[((cy * 3 + cx) * 4 + n) * 256 + oc] = s;
            }
}

// ------ epilogue: shared-T trick: all 6 heads use T = sum_n mix_n*relu ------
__global__ __launch_bounds__(256) void final_kernel(
    const float* __restrict__ mix, const ushort* __restrict__ U,
    const float* __restrict__ btab,
    const float* __restrict__ w_cls, const float* __restrict__ b_cls,
    const float* __restrict__ w_mean, const float* __restrict__ b_mean,
    const float* __restrict__ im_info,
    float* __restrict__ out,
    int H, int W, int out_base, int TOT, float stride_)
{
    const int pos = blockIdx.x * 256 + threadIdx.x;
    const int b = blockIdx.z;
    const int HW = H * W;
    if (pos >= HW) return;
    const int y = pos / W, x = pos % W;
    const int cy = (y == 0) ? 0 : ((y == H - 1) ? 2 : 1);
    const int cx = (x == 0) ? 0 : ((x == W - 1) ? 2 : 1);
    const float* bp = btab + (size_t)((cy * 3 + cx) * 4) * 256;

    const float* mp = mix + (size_t)b * 4 * HW + pos;
    const float m0 = mp[0], m1 = mp[HW];
    const float m2 = mp[2*(size_t)HW], m3 = mp[3*(size_t)HW];

    float sc0 = b_cls[0], sc1 = b_cls[1];
    float D0 = b_mean[0], D1 = b_mean[1], D2 = b_mean[2], D3 = b_mean[3];

    const ushort* up = U + (size_t)b * 256 * HW + pos;
    for (int oc = 0; oc < 256; ++oc) {
        const float u = bf2f(up[(size_t)oc * HW]);
        float T =      m0 * fmaxf(u + bp[oc      ], 0.f);
        T = fmaf(m1, fmaxf(u + bp[256 + oc], 0.f), T);
        T = fmaf(m2, fmaxf(u + bp[512 + oc], 0.f), T);
        T = fmaf(m3, fmaxf(u + bp[768 + oc], 0.f), T);
        sc0 = fmaf(w_cls[oc],        T, sc0);
        sc1 = fmaf(w_cls[256 + oc],  T, sc1);
        D0  = fmaf(w_mean[oc],       T, D0);
        D1  = fmaf(w_mean[256 + oc], T, D1);
        D2  = fmaf(w_mean[512 + oc], T, D2);
        D3  = fmaf(w_mean[768 + oc], T, D3);
    }

    const float aw  = stride_ * 8.f;
    const float acx = (x + 0.5f) * stride_;
    const float acy = (y + 0.5f) * stride_;
    const float cxx = acx + D0 * aw;
    const float cyy = acy + D1 * aw;
    const float e2 = fminf(fmaxf(D2, -10.f), 10.f);
    const float e3 = fminf(fmaxf(D3, -10.f), 10.f);
    const float bw = aw * expf(e2);
    const float bh = aw * expf(e3);
    const float imH = im_info[b * 6 + 0], imW = im_info[b * 6 + 1];
    const float x1 = fminf(fmaxf(cxx - 0.5f * bw, 0.f), imW);
    const float y1 = fminf(fmaxf(cyy - 0.5f * bh, 0.f), imH);
    const float x2 = fminf(fmaxf(cxx + 0.5f * bw, 0.f), imW);
    const float y2 = fminf(fmaxf(cyy + 0.5f * bh, 0.f), imH);

    float* op = out + ((size_t)b * TOT + out_base + pos) * 6;
    op[0] = x1; op[1] = y1; op[2] = x2; op[3] = y2; op[4] = sc0; op[5] = sc1;
}

// ---------------------------------------------------------------------------
extern "C" void kernel_launch(void* const* d_in, const int* in_sizes, int n_in,
                              void* d_out, int out_size, void* d_ws, size_t ws_size,
                              hipStream_t stream)
{
    (void)in_sizes; (void)n_in; (void)out_size; (void)ws_size;

    const float* feats[5] = { (const float*)d_in[0], (const float*)d_in[1],
                              (const float*)d_in[2], (const float*)d_in[3],
                              (const float*)d_in[4] };
    const float* im_info = (const float*)d_in[5];
    const float* b_qy1 = (const float*)d_in[7];
    const float* b_qy2 = (const float*)d_in[9];
    const float* w_qy  = (const float*)d_in[10];
    const float* b_qy  = (const float*)d_in[11];
    const float* w_rpn = (const float*)d_in[12];
    const float* b_rpn = (const float*)d_in[13];
    const float* w_cls = (const float*)d_in[14];
    const float* b_cls = (const float*)d_in[15];
    const float* w_mean= (const float*)d_in[16];
    const float* b_mean= (const float*)d_in[17];
    float* out = (float*)d_out;

    // ---- workspace layout (all 16B aligned) ----
    const size_t XBF_ELEMS = 41470464;   // 2*256*80997 bf16 feats
    const size_t BIGE      = 31129600;   // 2*256*60800 (max level)
    ushort* XBF = (ushort*)d_ws;
    ushort* A   = XBF + XBF_ELEMS;       // h1, then U
    ushort* Bb  = A + BIGE;              // h2
    float*  MIX = (float*)(Bb + BIGE);   // [B,4,HW] softmax weights
    float*  btab= MIX + (size_t)2 * 4 * 60800;
    ushort* PW1 = (ushort*)(btab + 9216);
    ushort* PW2 = PW1 + 589824;
    ushort* PWR = PW2 + 589824;

    const int   Hs[5]  = {13, 25, 50, 100, 200};
    const int   Ws5[5] = {19, 38, 76, 152, 304};
    const float st[5]  = {64.f, 32.f, 16.f, 8.f, 4.f};
    const int TOT = 80997;

    // per-level bf16 feature offsets (elements)
    size_t xoff[5]; size_t acc_off = 0;
    for (int L = 0; L < 5; ++L) { xoff[L] = acc_off; acc_off += (size_t)2 * 256 * Hs[L] * Ws5[L]; }

    // ---- one-time prep (runs every launch; ~60us total) ----
    for (int L = 0; L < 5; ++L) {
        int n4 = (2 * 256 * Hs[L] * Ws5[L]) / 4;
        cvt_bf16_kernel<<<(n4 + 255) / 256, 256, 0, stream>>>(feats[L], XBF + xoff[L], n4);
    }
    pack_w_kernel<<<2304, 256, 0, stream>>>((const float*)d_in[6], PW1, 256);
    pack_w_kernel<<<2304, 256, 0, stream>>>((const float*)d_in[8], PW2, 256);
    pack_w_kernel<<<2304, 256, 0, stream>>>(w_rpn, PWR, 260);
    bias_table_kernel<<<1, 256, 0, stream>>>(w_rpn, btab);

    int base = 0;
    for (int L = 0; L < 5; ++L) {
        const int H = Hs[L], W = Ws5[L], HW = H * W;
        const int tilesX = (W + 15) / 16;
        const int tilesY = (H + 7) / 8;
        dim3 gconv(tilesX * tilesY, 2, 2);
        dim3 gpos((HW + 255) / 256, 1, 2);

        // h1 = relu(conv(x, w_qy1))
        conv3x3_mfma<<<gconv, 256, 0, stream>>>(XBF + xoff[L], PW1, b_qy1, A, H, W, tilesX, 1);
        // h2 = relu(conv(h1, w_qy2))
        conv3x3_mfma<<<gconv, 256, 0, stream>>>(A, PW2, b_qy2, Bb, H, W, tilesX, 1);
        // mix = softmax(conv(h2, w_qy) + b_qy)
        qy_softmax_kernel<<<gpos, 256, 0, stream>>>(Bb, w_qy, b_qy, MIX, H, W);
        // U = conv(x, w_rpn[:, :256]) + b_rpn (shared across components)
        conv3x3_mfma<<<gconv, 256, 0, stream>>>(XBF + xoff[L], PWR, b_rpn, A, H, W, tilesX, 0);
        // heads + mixture + decode + clip
        final_kernel<<<gpos, 256, 0, stream>>>(MIX, A, btab, w_cls, b_cls,
                                               w_mean, b_mean, im_info, out,
                                               H, W, base, TOT, st[L]);
        base += HW;
    }
}

// Round 3
// 2340.944 us; speedup vs baseline: 5.5519x; 1.7979x over previous
//
#include <hip/hip_runtime.h>
#include <math.h>

// ---------------------------------------------------------------------------
// RPN GMM head, MI355X. Round 3: NHWC activations for conv inputs, merged
// per-stage dispatches across FPN levels, conv1+convR fused in one dispatch.
// conv3x3(concat[x, onehot_n], w_rpn) == conv3x3(x, w_rpn[:,:256]) + edge bias
// Conv = 9 tap-GEMMs, 128oc x 128pos tile, mfma_f32_16x16x32_bf16.
// Staging: NHWC -> one LDS site (64ic) = 128B contiguous = 8 lanes x ushort8.
// ---------------------------------------------------------------------------

typedef __attribute__((ext_vector_type(8))) short short8;
typedef __attribute__((ext_vector_type(4))) float f32x4;

#define TOT 80997

struct Tab {
    int tilesX[5];
    int blkBase[6];   // conv tile prefix over levels
    int H[5];
    int W5[5];
    int poff[6];      // position prefix over levels
    int cvtBase[6];   // 64-pos transpose-tile prefix
};

static __device__ __forceinline__ ushort f2bf(float f) {
    union { float f; unsigned u; } x; x.f = f;
    unsigned r = (x.u + 0x7FFFu + ((x.u >> 16) & 1u)) >> 16;  // RNE
    return (ushort)r;
}
static __device__ __forceinline__ float bf2f(ushort u) {
    union { unsigned u; float f; } x; x.u = ((unsigned)u) << 16;
    return x.f;
}

// -------- NCHW fp32 -> NHWC bf16 transpose-convert (64-pos x 256-ic tiles) --
__global__ __launch_bounds__(256) void cvtT_kernel(
    const float* __restrict__ f0, const float* __restrict__ f1,
    const float* __restrict__ f2, const float* __restrict__ f3,
    const float* __restrict__ f4, ushort* __restrict__ xn, Tab tab)
{
    __shared__ __align__(16) ushort s[64 * 264];   // pos-major, ic-stride 264
    const int tid = threadIdx.x;
    int t = blockIdx.x, L = 0;
    while (t >= tab.cvtBase[L + 1]) ++L;
    const int tile = t - tab.cvtBase[L];
    const int HW = tab.H[L] * tab.W5[L];
    const int pos0 = tile * 64;
    const int b = blockIdx.z;
    const float* fs[5] = {f0, f1, f2, f3, f4};
    const float* xp = fs[L] + (size_t)b * 256 * HW;

    const int p = tid & 63;
    const int icr = tid >> 6;
    const int pos = pos0 + p;
    for (int ic4 = 0; ic4 < 256; ic4 += 4) {
        const int ic = ic4 + icr;
        float v = 0.f;
        if (pos < HW) v = xp[(size_t)ic * HW + pos];   // lanes coalesced
        s[p * 264 + ic] = f2bf(v);
    }
    __syncthreads();
    const int seg = tid & 31;
    for (int k = 0; k < 8; ++k) {
        const int pp = (tid >> 5) + k * 8;
        const int gpos = pos0 + pp;
        if (gpos < HW) {
            short8 v = *(const short8*)&s[pp * 264 + seg * 8];
            *(short8*)(xn + ((size_t)b * TOT + tab.poff[L] + gpos) * 256 + seg * 8) = v;
        }
    }
}

// -------- weight pack: w[oc][ic][ky][kx] fp32 -> pw[tap][oc][ic] bf16 ------
__global__ __launch_bounds__(256) void pack_w_kernel(
    const float* __restrict__ w, ushort* __restrict__ pw, int icfull)
{
    int idx = blockIdx.x * 256 + threadIdx.x;   // 9*256*256
    if (idx >= 589824) return;
    int ic  = idx & 255;
    int oc  = (idx >> 8) & 255;
    int tap = idx >> 16;
    pw[idx] = f2bf(w[((size_t)oc * icfull + ic) * 9 + tap]);
}

// ------------------- big 3x3 conv: 256 -> 256, bf16 MFMA -------------------
// grid: (sum tiles, 2 oc-halves, B*jobs), block 256 = 4 waves.
// Tile: 128 oc x (16x x 8y) pos. Wave: 64oc x 64pos, 4x4 mfma 16x16 tiles.
__global__ __launch_bounds__(256, 4) void conv3x3_mfma(
    const ushort* __restrict__ inN,   // NHWC bf16 [b][TOT][256]
    const ushort* __restrict__ pw0, const ushort* __restrict__ pw1,
    const float* __restrict__ bias0, const float* __restrict__ bias1,
    ushort* __restrict__ out0, ushort* __restrict__ out1,
    int jobs, int nhwcFlags, int reluFlags, Tab tab)
{
    __shared__ __align__(16) ushort s_in[10 * 18 * 72];  // 25,920 B

    const int tid = threadIdx.x;
    int t = blockIdx.x, L = 0;
    while (t >= tab.blkBase[L + 1]) ++L;
    const int rel = t - tab.blkBase[L];
    const int tX = tab.tilesX[L];
    const int H = tab.H[L], W = tab.W5[L];
    const int HW = H * W;
    const int y0 = (rel / tX) * 8;
    const int x0 = (rel % tX) * 16;
    const int oc0 = blockIdx.y * 128;
    const int b   = blockIdx.z / jobs;
    const int job = blockIdx.z % jobs;
    const ushort* pw   = job ? pw1 : pw0;
    const float*  bias = job ? bias1 : bias0;
    ushort*       out  = job ? out1 : out0;
    const int nhwc = (nhwcFlags >> job) & 1;
    const int relu = (reluFlags >> job) & 1;
    const int poff = tab.poff[L];
    const size_t posB = (size_t)b * TOT + poff;

    const int lane = tid & 63;
    const int wave = tid >> 6;
    const int lm   = lane & 15;
    const int quad = lane >> 4;
    const int wrow = wave >> 1;   // oc half within 128
    const int wcol = wave & 1;    // y quad

    f32x4 acc[4][4];
#pragma unroll
    for (int i = 0; i < 4; ++i)
#pragma unroll
        for (int j = 0; j < 4; ++j) acc[i][j] = (f32x4){0.f, 0.f, 0.f, 0.f};

    const ushort* pwl = pw + (size_t)(oc0 + wrow * 64 + lm) * 256 + quad * 8;
    const int site0 = tid >> 3;   // 8 lanes per site
    const int icg   = tid & 7;

#pragma unroll 1
    for (int ic0i = 0; ic0i < 256; ic0i += 64) {
        __syncthreads();
        // stage: 180 sites (10 rows x 18 x), each 64 ic = 128 B contiguous
        for (int s0 = 0; s0 < 180; s0 += 32) {
            const int site = s0 + site0;
            if (site < 180) {
                const int r  = site / 18;
                const int xx = site - r * 18;
                const int yi = y0 - 1 + r, xi = x0 - 1 + xx;
                short8 v = {0, 0, 0, 0, 0, 0, 0, 0};
                if (yi >= 0 && yi < H && xi >= 0 && xi < W)
                    v = *(const short8*)(inN + (posB + (size_t)yi * W + xi) * 256
                                         + ic0i + icg * 8);
                *(short8*)&s_in[site * 72 + icg * 8] = v;
            }
        }
        __syncthreads();

#pragma unroll
        for (int sub = 0; sub < 2; ++sub)
#pragma unroll
        for (int kx = 0; kx < 3; ++kx) {
            short8 bv[6];   // 6 rows cover j+ky in [0,6)
#pragma unroll
            for (int r = 0; r < 6; ++r)
                bv[r] = *(const short8*)&s_in[((wcol * 4 + r) * 18 + lm + kx) * 72
                                              + quad * 8 + sub * 32];
#pragma unroll
            for (int ky = 0; ky < 3; ++ky) {
                const ushort* pa = pwl + (ky * 3 + kx) * 65536 + ic0i + sub * 32;
                short8 av[4];
#pragma unroll
                for (int i = 0; i < 4; ++i) av[i] = *(const short8*)(pa + i * 4096);
#pragma unroll
                for (int i = 0; i < 4; ++i)
#pragma unroll
                    for (int j = 0; j < 4; ++j)
                        acc[i][j] = __builtin_amdgcn_mfma_f32_16x16x32_bf16(
                            av[i], bv[j + ky], acc[i][j], 0, 0, 0);
            }
        }
    }

    // epilogue: D layout col=lane&15 (x), row=quad*4+reg (oc)
    const int x = x0 + lm;
    if (x >= W) return;
    if (nhwc) {
#pragma unroll
        for (int i = 0; i < 4; ++i) {
            const int ocb = oc0 + wrow * 64 + i * 16 + quad * 4;
            const float4 bv4 = *(const float4*)(bias + ocb);
#pragma unroll
            for (int j = 0; j < 4; ++j) {
                const int y = y0 + wcol * 4 + j;
                if (y < H) {
                    float v0 = acc[i][j][0] + bv4.x;
                    float v1 = acc[i][j][1] + bv4.y;
                    float v2 = acc[i][j][2] + bv4.z;
                    float v3 = acc[i][j][3] + bv4.w;
                    if (relu) {
                        v0 = fmaxf(v0, 0.f); v1 = fmaxf(v1, 0.f);
                        v2 = fmaxf(v2, 0.f); v3 = fmaxf(v3, 0.f);
                    }
                    ushort4 o;
                    o.x = f2bf(v0); o.y = f2bf(v1); o.z = f2bf(v2); o.w = f2bf(v3);
                    *(ushort4*)(out + (posB + (size_t)y * W + x) * 256 + ocb) = o;
                }
            }
        }
    } else {
        const size_t nb = (size_t)512 * poff + (size_t)(b * 256) * HW;
#pragma unroll
        for (int i = 0; i < 4; ++i) {
            const int ocb = oc0 + wrow * 64 + i * 16 + quad * 4;
            const float4 bv4 = *(const float4*)(bias + ocb);
            const float ba[4] = {bv4.x, bv4.y, bv4.z, bv4.w};
#pragma unroll
            for (int j = 0; j < 4; ++j) {
                const int y = y0 + wcol * 4 + j;
                if (y < H) {
#pragma unroll
                    for (int reg = 0; reg < 4; ++reg) {
                        float v = acc[i][j][reg] + ba[reg];
                        if (relu) v = fmaxf(v, 0.f);
                        out[nb + (size_t)(ocb + reg) * HW + (size_t)y * W + x] = f2bf(v);
                    }
                }
            }
        }
    }
}

// ---------------- qy conv (256->4, 3x3) fused with softmax -> mix ----------
__global__ __launch_bounds__(256) void qy_softmax_kernel(
    const ushort* __restrict__ h2, const float* __restrict__ wqy,
    const float* __restrict__ bqy, float* __restrict__ mix, Tab tab)
{
    int p = blockIdx.x * 256 + threadIdx.x;
    if (p >= TOT) return;
    int L = 0; while (p >= tab.poff[L + 1]) ++L;
    const int pos = p - tab.poff[L];
    const int H = tab.H[L], W = tab.W5[L], HW = H * W;
    const int b = blockIdx.z;
    const int y = pos / W, x = pos % W;

    int   offt[9];
    float mskt[9];
#pragma unroll
    for (int ky = 0; ky < 3; ++ky)
#pragma unroll
        for (int kx = 0; kx < 3; ++kx) {
            int tt = ky * 3 + kx;
            int yi = y + ky - 1, xi = x + kx - 1;
            bool v = (yi >= 0 && yi < H && xi >= 0 && xi < W);
            offt[tt] = v ? yi * W + xi : 0;
            mskt[tt] = v ? 1.f : 0.f;
        }

    float a0 = bqy[0], a1 = bqy[1], a2 = bqy[2], a3 = bqy[3];
    const ushort* inb = h2 + (size_t)512 * tab.poff[L] + (size_t)(b * 256) * HW;
    for (int ic = 0; ic < 256; ++ic) {
        const ushort* ip = inb + (size_t)ic * HW;
        const float* wp = wqy + ic * 9;
#pragma unroll
        for (int tt = 0; tt < 9; ++tt) {
            float v = bf2f(ip[offt[tt]]) * mskt[tt];
            a0 = fmaf(wp[tt       ], v, a0);
            a1 = fmaf(wp[tt + 2304], v, a1);
            a2 = fmaf(wp[tt + 4608], v, a2);
            a3 = fmaf(wp[tt + 6912], v, a3);
        }
    }
    float mx = fmaxf(fmaxf(a0, a1), fmaxf(a2, a3));
    float e0 = expf(a0 - mx), e1 = expf(a1 - mx);
    float e2 = expf(a2 - mx), e3 = expf(a3 - mx);
    float s = 1.f / (e0 + e1 + e2 + e3);
    float* mp = mix + (size_t)8 * tab.poff[L] + (size_t)(b * 4) * HW + pos;
    mp[0]              = e0 * s;
    mp[HW]             = e1 * s;
    mp[2 * (size_t)HW] = e2 * s;
    mp[3 * (size_t)HW] = e3 * s;
}

// ------------- edge-bias table: btab[cy][cx][n][oc], 3*3*4*256 -------------
__global__ void bias_table_kernel(const float* __restrict__ w_rpn,
                                  float* __restrict__ btab)
{
    const int oc = threadIdx.x;  // 256 threads
    for (int cy = 0; cy < 3; ++cy)
        for (int cx = 0; cx < 3; ++cx)
            for (int n = 0; n < 4; ++n) {
                float s = 0.f;
                for (int ky = 0; ky < 3; ++ky) {
                    if (cy == 0 && ky == 0) continue;
                    if (cy == 2 && ky == 2) continue;
                    for (int kx = 0; kx < 3; ++kx) {
                        if (cx == 0 && kx == 0) continue;
                        if (cx == 2 && kx == 2) continue;
                        s += w_rpn[(size_t)oc * 2340 + (256 + n) * 9 + ky * 3 + kx];
                    }
                }
                btab[((cy * 3 + cx) * 4 + n) * 256 + oc] = s;
            }
}

// ------ epilogue: T = sum_n mix_n*relu(u+bias_n) shared by all 6 heads -----
__global__ __launch_bounds__(256) void final_kernel(
    const float* __restrict__ mix, const ushort* __restrict__ U,
    const float* __restrict__ btab,
    const float* __restrict__ w_cls, const float* __restrict__ b_cls,
    const float* __restrict__ w_mean, const float* __restrict__ b_mean,
    const float* __restrict__ im_info,
    float* __restrict__ out, Tab tab)
{
    int p = blockIdx.x * 256 + threadIdx.x;
    if (p >= TOT) return;
    int L = 0; while (p >= tab.poff[L + 1]) ++L;
    const int pos = p - tab.poff[L];
    const int H = tab.H[L], W = tab.W5[L], HW = H * W;
    const int b = blockIdx.z;
    const float stride_ = (float)(64 >> L);
    const int y = pos / W, x = pos % W;
    const int cy = (y == 0) ? 0 : ((y == H - 1) ? 2 : 1);
    const int cx = (x == 0) ? 0 : ((x == W - 1) ? 2 : 1);
    const float* bp = btab + (size_t)((cy * 3 + cx) * 4) * 256;

    const float* mp = mix + (size_t)8 * tab.poff[L] + (size_t)(b * 4) * HW + pos;
    const float m0 = mp[0], m1 = mp[HW];
    const float m2 = mp[2 * (size_t)HW], m3 = mp[3 * (size_t)HW];

    float sc0 = b_cls[0], sc1 = b_cls[1];
    float D0 = b_mean[0], D1 = b_mean[1], D2 = b_mean[2], D3 = b_mean[3];

    const ushort* up = U + (size_t)512 * tab.poff[L] + (size_t)(b * 256) * HW + pos;
    for (int oc = 0; oc < 256; ++oc) {
        const float u = bf2f(up[(size_t)oc * HW]);
        float T =      m0 * fmaxf(u + bp[oc      ], 0.f);
        T = fmaf(m1, fmaxf(u + bp[256 + oc], 0.f), T);
        T = fmaf(m2, fmaxf(u + bp[512 + oc], 0.f), T);
        T = fmaf(m3, fmaxf(u + bp[768 + oc], 0.f), T);
        sc0 = fmaf(w_cls[oc],        T, sc0);
        sc1 = fmaf(w_cls[256 + oc],  T, sc1);
        D0  = fmaf(w_mean[oc],       T, D0);
        D1  = fmaf(w_mean[256 + oc], T, D1);
        D2  = fmaf(w_mean[512 + oc], T, D2);
        D3  = fmaf(w_mean[768 + oc], T, D3);
    }

    const float aw  = stride_ * 8.f;
    const float acx = (x + 0.5f) * stride_;
    const float acy = (y + 0.5f) * stride_;
    const float cxx = acx + D0 * aw;
    const float cyy = acy + D1 * aw;
    const float e2 = fminf(fmaxf(D2, -10.f), 10.f);
    const float e3 = fminf(fmaxf(D3, -10.f), 10.f);
    const float bw = aw * expf(e2);
    const float bh = aw * expf(e3);
    const float imH = im_info[b * 6 + 0], imW = im_info[b * 6 + 1];
    const float x1 = fminf(fmaxf(cxx - 0.5f * bw, 0.f), imW);
    const float y1 = fminf(fmaxf(cyy - 0.5f * bh, 0.f), imH);
    const float x2 = fminf(fmaxf(cxx + 0.5f * bw, 0.f), imW);
    const float y2 = fminf(fmaxf(cyy + 0.5f * bh, 0.f), imH);

    float* op = out + ((size_t)b * TOT + p) * 6;
    op[0] = x1; op[1] = y1; op[2] = x2; op[3] = y2; op[4] = sc0; op[5] = sc1;
}

// ---------------------------------------------------------------------------
extern "C" void kernel_launch(void* const* d_in, const int* in_sizes, int n_in,
                              void* d_out, int out_size, void* d_ws, size_t ws_size,
                              hipStream_t stream)
{
    (void)in_sizes; (void)n_in; (void)out_size; (void)ws_size;

    const float* im_info = (const float*)d_in[5];
    const float* w_qy1 = (const float*)d_in[6];
    const float* b_qy1 = (const float*)d_in[7];
    const float* w_qy2 = (const float*)d_in[8];
    const float* b_qy2 = (const float*)d_in[9];
    const float* w_qy  = (const float*)d_in[10];
    const float* b_qy  = (const float*)d_in[11];
    const float* w_rpn = (const float*)d_in[12];
    const float* b_rpn = (const float*)d_in[13];
    const float* w_cls = (const float*)d_in[14];
    const float* b_cls = (const float*)d_in[15];
    const float* w_mean= (const float*)d_in[16];
    const float* b_mean= (const float*)d_in[17];
    float* out = (float*)d_out;

    // ---- level tables ----
    Tab tab;
    const int Hs[5]  = {13, 25, 50, 100, 200};
    const int Ws5[5] = {19, 38, 76, 152, 304};
    int bsum = 0, psum = 0, csum = 0;
    for (int L = 0; L < 5; ++L) {
        tab.H[L] = Hs[L]; tab.W5[L] = Ws5[L];
        tab.tilesX[L] = (Ws5[L] + 15) / 16;
        tab.blkBase[L] = bsum;
        bsum += tab.tilesX[L] * ((Hs[L] + 7) / 8);
        tab.poff[L] = psum;
        tab.cvtBase[L] = csum;
        const int HW = Hs[L] * Ws5[L];
        psum += HW;
        csum += (HW + 63) / 64;
    }
    tab.blkBase[5] = bsum; tab.poff[5] = psum; tab.cvtBase[5] = csum;

    // ---- workspace layout (all 16B-aligned) ----
    const size_t BIGE = (size_t)2 * TOT * 256;   // 41,470,464 elems (82.9 MB)
    ushort* XN  = (ushort*)d_ws;                 // x NHWC; later aliased by H2
    ushort* H1  = XN + BIGE;                     // h1 NHWC
    ushort* U   = H1 + BIGE;                     // U NCHW (per-level blocks)
    ushort* H2  = XN;                            // h2 NCHW, aliases dead XN
    float*  MIX = (float*)(U + BIGE);            // [L][b][4][HW]
    float*  btab= MIX + (size_t)8 * TOT;
    ushort* PW1 = (ushort*)(btab + 9216);
    ushort* PW2 = PW1 + 589824;
    ushort* PWR = PW2 + 589824;

    // ---- prep ----
    cvtT_kernel<<<dim3(csum, 1, 2), 256, 0, stream>>>(
        (const float*)d_in[0], (const float*)d_in[1], (const float*)d_in[2],
        (const float*)d_in[3], (const float*)d_in[4], XN, tab);
    pack_w_kernel<<<2304, 256, 0, stream>>>(w_qy1, PW1, 256);
    pack_w_kernel<<<2304, 256, 0, stream>>>(w_qy2, PW2, 256);
    pack_w_kernel<<<2304, 256, 0, stream>>>(w_rpn, PWR, 260);
    bias_table_kernel<<<1, 256, 0, stream>>>(w_rpn, btab);

    // ---- D1: conv1 (x->h1, NHWC, relu) + convR (x->U, NCHW) fused ----
    conv3x3_mfma<<<dim3(bsum, 2, 4), 256, 0, stream>>>(
        XN, PW1, PWR, b_qy1, b_rpn, H1, U, /*jobs=*/2,
        /*nhwcFlags=*/0b01, /*reluFlags=*/0b01, tab);

    // ---- D2: conv2 (h1->h2, NCHW, relu) ----
    conv3x3_mfma<<<dim3(bsum, 2, 2), 256, 0, stream>>>(
        H1, PW2, PW2, b_qy2, b_qy2, H2, H2, /*jobs=*/1,
        /*nhwcFlags=*/0b00, /*reluFlags=*/0b01, tab);

    // ---- D3: qy conv + softmax ----
    qy_softmax_kernel<<<dim3((TOT + 255) / 256, 1, 2), 256, 0, stream>>>(
        H2, w_qy, b_qy, MIX, tab);

    // ---- D4: heads + mixture + decode + clip ----
    final_kernel<<<dim3((TOT + 255) / 256, 1, 2), 256, 0, stream>>>(
        MIX, U, btab, w_cls, b_cls, w_mean, b_mean, im_info, out, tab);
}

// Round 4
// 2328.587 us; speedup vs baseline: 5.5814x; 1.0053x over previous
//
#include <hip/hip_runtime.h>
#include <math.h>

// ---------------------------------------------------------------------------
// RPN GMM head, MI355X. Round 4: all-NHWC, LDS-transposed conv epilogue
// (full-line stores, no L2 RMW), conflict-minimal LDS layouts, vectorized
// NHWC consumers (final / qy) with 4-lanes-per-position + shfl reduction.
// conv3x3(concat[x, onehot_n], w_rpn) == conv3x3(x, w_rpn[:,:256]) + edge bias
// Conv = 9 tap-GEMMs, 128oc x (16x*8y)pos tile, mfma_f32_16x16x32_bf16.
// ---------------------------------------------------------------------------

typedef __attribute__((ext_vector_type(8))) short short8;
typedef __attribute__((ext_vector_type(4))) float f32x4;

#define TOT 80997

struct Tab {
    int tilesX[5];
    int blkBase[6];
    int H[5];
    int W5[5];
    int poff[6];
    int cvtBase[6];
};

static __device__ __forceinline__ ushort f2bf(float f) {
    union { float f; unsigned u; } x; x.f = f;
    unsigned r = (x.u + 0x7FFFu + ((x.u >> 16) & 1u)) >> 16;  // RNE
    return (ushort)r;
}
static __device__ __forceinline__ float bf2f(ushort u) {
    union { unsigned u; float f; } x; x.u = ((unsigned)u) << 16;
    return x.f;
}

// -------- NCHW fp32 -> NHWC bf16 transpose-convert (64-pos x 256-ic tiles) --
__global__ __launch_bounds__(256) void cvtT_kernel(
    const float* __restrict__ f0, const float* __restrict__ f1,
    const float* __restrict__ f2, const float* __restrict__ f3,
    const float* __restrict__ f4, ushort* __restrict__ xn, Tab tab)
{
    __shared__ __align__(16) ushort s[64 * 264];
    const int tid = threadIdx.x;
    int t = blockIdx.x, L = 0;
    while (t >= tab.cvtBase[L + 1]) ++L;
    const int tile = t - tab.cvtBase[L];
    const int HW = tab.H[L] * tab.W5[L];
    const int pos0 = tile * 64;
    const int b = blockIdx.z;
    const float* fs[5] = {f0, f1, f2, f3, f4};
    const float* xp = fs[L] + (size_t)b * 256 * HW;

    const int p = tid & 63;
    const int icr = tid >> 6;
    const int pos = pos0 + p;
    for (int ic4 = 0; ic4 < 256; ic4 += 4) {
        const int ic = ic4 + icr;
        float v = 0.f;
        if (pos < HW) v = xp[(size_t)ic * HW + pos];
        s[p * 264 + ic] = f2bf(v);
    }
    __syncthreads();
    const int seg = tid & 31;
    for (int k = 0; k < 8; ++k) {
        const int pp = (tid >> 5) + k * 8;
        const int gpos = pos0 + pp;
        if (gpos < HW) {
            short8 v = *(const short8*)&s[pp * 264 + seg * 8];
            *(short8*)(xn + ((size_t)b * TOT + tab.poff[L] + gpos) * 256 + seg * 8) = v;
        }
    }
}

// -------- weight pack: w[oc][ic][ky][kx] fp32 -> pw[tap][oc][ic] bf16 ------
__global__ __launch_bounds__(256) void pack_w_kernel(
    const float* __restrict__ w, ushort* __restrict__ pw, int icfull)
{
    int idx = blockIdx.x * 256 + threadIdx.x;
    if (idx >= 589824) return;
    int ic  = idx & 255;
    int oc  = (idx >> 8) & 255;
    int tap = idx >> 16;
    pw[idx] = f2bf(w[((size_t)oc * icfull + ic) * 9 + tap]);
}

// -------- qy weight pack: wqy[n][ic][tap] fp32 -> pwqy[n][tap][ic] bf16 ----
__global__ __launch_bounds__(256) void pack_qy_kernel(
    const float* __restrict__ wqy, ushort* __restrict__ pwqy)
{
    int idx = blockIdx.x * 256 + threadIdx.x;   // 4*9*256 = 9216
    if (idx >= 9216) return;
    int ic = idx & 255;
    int t  = (idx >> 8) % 9;
    int n  = (idx >> 8) / 9;
    pwqy[idx] = f2bf(wqy[n * 2304 + ic * 9 + t]);
}

// ---- edge-bias table, transposed: btabT[case][oc][n] (float4 per oc) ------
__global__ __launch_bounds__(256) void btabT_kernel(
    const float* __restrict__ w_rpn, float* __restrict__ btabT)
{
    int idx = blockIdx.x * 256 + threadIdx.x;   // 9*256
    if (idx >= 2304) return;
    const int oc = idx & 255;
    const int cs = idx >> 8;
    const int cy = cs / 3, cx = cs % 3;
    float4 o;
    float* op = (float*)&o;
    for (int n = 0; n < 4; ++n) {
        float s = 0.f;
        for (int ky = 0; ky < 3; ++ky) {
            if (cy == 0 && ky == 0) continue;
            if (cy == 2 && ky == 2) continue;
            for (int kx = 0; kx < 3; ++kx) {
                if (cx == 0 && kx == 0) continue;
                if (cx == 2 && kx == 2) continue;
                s += w_rpn[(size_t)oc * 2340 + (256 + n) * 9 + ky * 3 + kx];
            }
        }
        op[n] = s;
    }
    ((float4*)btabT)[cs * 256 + oc] = o;
}

// -------- head weight pack: wcp[oc]={cls0,cls1}, wmp[oc]={m0..m3} ----------
__global__ void pack_head_kernel(const float* __restrict__ w_cls,
                                 const float* __restrict__ w_mean,
                                 float* __restrict__ wcp, float* __restrict__ wmp)
{
    const int oc = threadIdx.x;  // 256
    wcp[oc * 2]     = w_cls[oc];
    wcp[oc * 2 + 1] = w_cls[256 + oc];
    float4 m;
    m.x = w_mean[oc];       m.y = w_mean[256 + oc];
    m.z = w_mean[512 + oc]; m.w = w_mean[768 + oc];
    ((float4*)wmp)[oc] = m;
}

// ------------------- big 3x3 conv: 256 -> 256, bf16 MFMA -------------------
// grid: (sum tiles, 2 oc-halves, B*jobs), block 256 = 4 waves.
// LDS: s_in [10 rows][8 icb][18 x][8 ic] (23 KB) unioned with
//      s_out [128 pos][136 oc] (34.8 KB) for the transposed epilogue.
__global__ __launch_bounds__(256, 4) void conv3x3_mfma(
    const ushort* __restrict__ inN,   // NHWC bf16 [b][TOT][256]
    const ushort* __restrict__ pw0, const ushort* __restrict__ pw1,
    const float* __restrict__ bias0, const float* __restrict__ bias1,
    ushort* __restrict__ out0, ushort* __restrict__ out1,
    int jobs, int reluFlags, Tab tab)
{
    __shared__ __align__(16) char smem[34816];
    ushort* s_in  = (ushort*)smem;   // [10][8][18][8]
    ushort* s_out = (ushort*)smem;   // [128][136]

    const int tid = threadIdx.x;
    int t = blockIdx.x, L = 0;
    while (t >= tab.blkBase[L + 1]) ++L;
    const int rel = t - tab.blkBase[L];
    const int tX = tab.tilesX[L];
    const int H = tab.H[L], W = tab.W5[L];
    const int y0 = (rel / tX) * 8;
    const int x0 = (rel % tX) * 16;
    const int oc0 = blockIdx.y * 128;
    const int b   = blockIdx.z / jobs;
    const int job = blockIdx.z % jobs;
    const ushort* pw   = job ? pw1 : pw0;
    const float*  bias = job ? bias1 : bias0;
    ushort*       out  = job ? out1 : out0;
    const int relu = (reluFlags >> job) & 1;
    const size_t posB = (size_t)b * TOT + tab.poff[L];

    const int lane = tid & 63;
    const int wave = tid >> 6;
    const int lm   = lane & 15;
    const int quad = lane >> 4;
    const int wrow = wave >> 1;   // oc half within 128
    const int wcol = wave & 1;    // y quad

    f32x4 acc[4][4];
#pragma unroll
    for (int i = 0; i < 4; ++i)
#pragma unroll
        for (int j = 0; j < 4; ++j) acc[i][j] = (f32x4){0.f, 0.f, 0.f, 0.f};

    const ushort* pwl = pw + (size_t)(oc0 + wrow * 64 + lm) * 256 + quad * 8;
    const int siteT = tid >> 3;   // 8 lanes per site
    const int icg   = tid & 7;

#pragma unroll 1
    for (int ic0i = 0; ic0i < 256; ic0i += 64) {
        __syncthreads();
        // stage: 180 sites (10 rows x 18 x); site's 64 ic = 128 B contiguous
        for (int s0 = 0; s0 < 180; s0 += 32) {
            const int site = s0 + siteT;
            if (site < 180) {
                const int r  = site / 18;
                const int xx = site - r * 18;
                const int yi = y0 - 1 + r, xi = x0 - 1 + xx;
                short8 v = {0, 0, 0, 0, 0, 0, 0, 0};
                if (yi >= 0 && yi < H && xi >= 0 && xi < W)
                    v = *(const short8*)(inN + (posB + (size_t)yi * W + xi) * 256
                                         + ic0i + icg * 8);
                *(short8*)&s_in[((r * 8 + icg) * 18 + xx) * 8] = v;
            }
        }
        __syncthreads();

#pragma unroll
        for (int sub = 0; sub < 2; ++sub) {
            const int icb = quad + sub * 4;
#pragma unroll
            for (int kx = 0; kx < 3; ++kx) {
                short8 bv[6];   // halo rows wcol*4 .. wcol*4+5
#pragma unroll
                for (int r = 0; r < 6; ++r)
                    bv[r] = *(const short8*)
                        &s_in[(((wcol * 4 + r) * 8 + icb) * 18 + lm + kx) * 8];
#pragma unroll
                for (int ky = 0; ky < 3; ++ky) {
                    const ushort* pa = pwl + (ky * 3 + kx) * 65536 + ic0i + sub * 32;
                    short8 av[4];
#pragma unroll
                    for (int i = 0; i < 4; ++i) av[i] = *(const short8*)(pa + i * 4096);
#pragma unroll
                    for (int i = 0; i < 4; ++i)
#pragma unroll
                        for (int j = 0; j < 4; ++j)
                            acc[i][j] = __builtin_amdgcn_mfma_f32_16x16x32_bf16(
                                av[i], bv[j + ky], acc[i][j], 0, 0, 0);
                }
            }
        }
    }

    __syncthreads();   // all MFMA LDS reads done before s_out overwrites s_in

    // bias + relu + cvt into s_out[pos 128][oc 136-padded]
#pragma unroll
    for (int i = 0; i < 4; ++i) {
        const int ocl = wrow * 64 + i * 16 + quad * 4;   // oc within 128
        const float4 bv4 = *(const float4*)(bias + oc0 + ocl);
#pragma unroll
        for (int j = 0; j < 4; ++j) {
            const int posL = (wcol * 4 + j) * 16 + lm;
            float v0 = acc[i][j][0] + bv4.x;
            float v1 = acc[i][j][1] + bv4.y;
            float v2 = acc[i][j][2] + bv4.z;
            float v3 = acc[i][j][3] + bv4.w;
            if (relu) {
                v0 = fmaxf(v0, 0.f); v1 = fmaxf(v1, 0.f);
                v2 = fmaxf(v2, 0.f); v3 = fmaxf(v3, 0.f);
            }
            ushort4 o;
            o.x = f2bf(v0); o.y = f2bf(v1); o.z = f2bf(v2); o.w = f2bf(v3);
            *(ushort4*)&s_out[posL * 136 + ocl] = o;
        }
    }
    __syncthreads();

    // coalesced store: per position, 128 oc = 256 B contiguous (16 lanes x 16B)
#pragma unroll
    for (int it = 0; it < 8; ++it) {
        const int idx = it * 256 + tid;
        const int p   = idx >> 4;
        const int sgm = idx & 15;
        const int y = y0 + (p >> 4), x = x0 + (p & 15);
        if (y < H && x < W)
            *(short8*)(out + (posB + (size_t)y * W + x) * 256 + oc0 + sgm * 8)
                = *(const short8*)&s_out[p * 136 + sgm * 8];
    }
}

// ------- qy conv (256->4, 3x3) + softmax; NHWC h2; 4 lanes per position ----
__global__ __launch_bounds__(256) void qy_softmax_kernel(
    const ushort* __restrict__ h2, const ushort* __restrict__ pwqy, // [4][9][256]
    const float* __restrict__ bqy, float* __restrict__ mixv, Tab tab)
{
    const int tid = threadIdx.x;
    const int p = blockIdx.x * 64 + (tid >> 2);
    if (p >= TOT) return;
    const int q = tid & 3;
    const int b = blockIdx.z;
    int L = 0; while (p >= tab.poff[L + 1]) ++L;
    const int pos = p - tab.poff[L];
    const int W = tab.W5[L], H = tab.H[L];
    const int y = pos / W, x = pos - y * W;

    int  off[9];
    bool val[9];
#pragma unroll
    for (int ky = 0; ky < 3; ++ky)
#pragma unroll
        for (int kx = 0; kx < 3; ++kx) {
            const int t = ky * 3 + kx;
            const int yi = y + ky - 1, xi = x + kx - 1;
            val[t] = (yi >= 0 && yi < H && xi >= 0 && xi < W);
            off[t] = ((ky - 1) * W + (kx - 1)) * 256;
        }

    float a0 = 0.f, a1 = 0.f, a2 = 0.f, a3 = 0.f;
    const ushort* hp = h2 + ((size_t)b * TOT + p) * 256;
#pragma unroll 1
    for (int k = 0; k < 8; ++k) {
        const int sb = (k * 4 + q) * 8;
#pragma unroll
        for (int t = 0; t < 9; ++t) {
            if (!val[t]) continue;
            const short8 h8 = *(const short8*)(hp + off[t] + sb);
            float hv[8];
#pragma unroll
            for (int e = 0; e < 8; ++e) hv[e] = bf2f((ushort)h8[e]);
            const short8 w0 = *(const short8*)(pwqy + (0 * 9 + t) * 256 + sb);
            const short8 w1 = *(const short8*)(pwqy + (1 * 9 + t) * 256 + sb);
            const short8 w2 = *(const short8*)(pwqy + (2 * 9 + t) * 256 + sb);
            const short8 w3 = *(const short8*)(pwqy + (3 * 9 + t) * 256 + sb);
#pragma unroll
            for (int e = 0; e < 8; ++e) {
                a0 = fmaf(bf2f((ushort)w0[e]), hv[e], a0);
                a1 = fmaf(bf2f((ushort)w1[e]), hv[e], a1);
                a2 = fmaf(bf2f((ushort)w2[e]), hv[e], a2);
                a3 = fmaf(bf2f((ushort)w3[e]), hv[e], a3);
            }
        }
    }
    a0 += __shfl_xor(a0, 1); a0 += __shfl_xor(a0, 2);
    a1 += __shfl_xor(a1, 1); a1 += __shfl_xor(a1, 2);
    a2 += __shfl_xor(a2, 1); a2 += __shfl_xor(a2, 2);
    a3 += __shfl_xor(a3, 1); a3 += __shfl_xor(a3, 2);
    if (q == 0) {
        a0 += bqy[0]; a1 += bqy[1]; a2 += bqy[2]; a3 += bqy[3];
        const float mx = fmaxf(fmaxf(a0, a1), fmaxf(a2, a3));
        const float e0 = expf(a0 - mx), e1 = expf(a1 - mx);
        const float e2 = expf(a2 - mx), e3 = expf(a3 - mx);
        const float s = 1.f / (e0 + e1 + e2 + e3);
        float4 o; o.x = e0 * s; o.y = e1 * s; o.z = e2 * s; o.w = e3 * s;
        ((float4*)mixv)[(size_t)b * TOT + p] = o;
    }
}

// ------ final: T = sum_n mix_n*relu(u+bias_n); 6 heads; decode; clip -------
__global__ __launch_bounds__(256) void final_kernel(
    const float* __restrict__ mixv, const ushort* __restrict__ U,
    const float* __restrict__ btabT,
    const float* __restrict__ wcp, const float* __restrict__ wmp,
    const float* __restrict__ b_cls, const float* __restrict__ b_mean,
    const float* __restrict__ im_info,
    float* __restrict__ outp, Tab tab)
{
    const int tid = threadIdx.x;
    const int p = blockIdx.x * 64 + (tid >> 2);
    if (p >= TOT) return;
    const int q = tid & 3;
    const int b = blockIdx.z;
    int L = 0; while (p >= tab.poff[L + 1]) ++L;
    const int pos = p - tab.poff[L];
    const int W = tab.W5[L], H = tab.H[L];
    const int y = pos / W, x = pos - y * W;
    const int cy = (y == 0) ? 0 : ((y == H - 1) ? 2 : 1);
    const int cx = (x == 0) ? 0 : ((x == W - 1) ? 2 : 1);
    const float* bT = btabT + (size_t)(cy * 3 + cx) * 1024;

    const float4 mm = ((const float4*)mixv)[(size_t)b * TOT + p];
    const ushort* up = U + ((size_t)b * TOT + p) * 256;

    float sc0 = 0.f, sc1 = 0.f, D0 = 0.f, D1 = 0.f, D2 = 0.f, D3 = 0.f;
#pragma unroll 1
    for (int k = 0; k < 8; ++k) {
        const int seg = k * 4 + q;
        const short8 u8 = *(const short8*)(up + seg * 8);
#pragma unroll
        for (int e = 0; e < 8; ++e) {
            const int oc = seg * 8 + e;
            const float u = bf2f((ushort)u8[e]);
            const float4 bt = *(const float4*)(bT + oc * 4);
            float T =      mm.x * fmaxf(u + bt.x, 0.f);
            T = fmaf(mm.y, fmaxf(u + bt.y, 0.f), T);
            T = fmaf(mm.z, fmaxf(u + bt.z, 0.f), T);
            T = fmaf(mm.w, fmaxf(u + bt.w, 0.f), T);
            const float2 wc = *(const float2*)(wcp + oc * 2);
            const float4 wm = *(const float4*)(wmp + oc * 4);
            sc0 = fmaf(wc.x, T, sc0); sc1 = fmaf(wc.y, T, sc1);
            D0 = fmaf(wm.x, T, D0);   D1 = fmaf(wm.y, T, D1);
            D2 = fmaf(wm.z, T, D2);   D3 = fmaf(wm.w, T, D3);
        }
    }
    sc0 += __shfl_xor(sc0, 1); sc0 += __shfl_xor(sc0, 2);
    sc1 += __shfl_xor(sc1, 1); sc1 += __shfl_xor(sc1, 2);
    D0  += __shfl_xor(D0, 1);  D0  += __shfl_xor(D0, 2);
    D1  += __shfl_xor(D1, 1);  D1  += __shfl_xor(D1, 2);
    D2  += __shfl_xor(D2, 1);  D2  += __shfl_xor(D2, 2);
    D3  += __shfl_xor(D3, 1);  D3  += __shfl_xor(D3, 2);

    if (q == 0) {
        sc0 += b_cls[0]; sc1 += b_cls[1];
        D0 += b_mean[0]; D1 += b_mean[1]; D2 += b_mean[2]; D3 += b_mean[3];
        const float stride_ = (float)(64 >> L);
        const float aw  = stride_ * 8.f;
        const float acx = (x + 0.5f) * stride_;
        const float acy = (y + 0.5f) * stride_;
        const float cxx = acx + D0 * aw;
        const float cyy = acy + D1 * aw;
        const float e2 = fminf(fmaxf(D2, -10.f), 10.f);
        const float e3 = fminf(fmaxf(D3, -10.f), 10.f);
        const float bw = aw * expf(e2);
        const float bh = aw * expf(e3);
        const float imH = im_info[b * 6 + 0], imW = im_info[b * 6 + 1];
        const float x1 = fminf(fmaxf(cxx - 0.5f * bw, 0.f), imW);
        const float y1 = fminf(fmaxf(cyy - 0.5f * bh, 0.f), imH);
        const float x2 = fminf(fmaxf(cxx + 0.5f * bw, 0.f), imW);
        const float y2 = fminf(fmaxf(cyy + 0.5f * bh, 0.f), imH);
        float* op = outp + ((size_t)b * TOT + p) * 6;
        float2 w01; w01.x = x1; w01.y = y1;
        float2 w23; w23.x = x2; w23.y = y2;
        float2 w45; w45.x = sc0; w45.y = sc1;
        ((float2*)op)[0] = w01; ((float2*)op)[1] = w23; ((float2*)op)[2] = w45;
    }
}

// ---------------------------------------------------------------------------
extern "C" void kernel_launch(void* const* d_in, const int* in_sizes, int n_in,
                              void* d_out, int out_size, void* d_ws, size_t ws_size,
                              hipStream_t stream)
{
    (void)in_sizes; (void)n_in; (void)out_size; (void)ws_size;

    const float* im_info = (const float*)d_in[5];
    const float* w_qy1 = (const float*)d_in[6];
    const float* b_qy1 = (const float*)d_in[7];
    const float* w_qy2 = (const float*)d_in[8];
    const float* b_qy2 = (const float*)d_in[9];
    const float* w_qy  = (const float*)d_in[10];
    const float* b_qy  = (const float*)d_in[11];
    const float* w_rpn = (const float*)d_in[12];
    const float* b_rpn = (const float*)d_in[13];
    const float* w_cls = (const float*)d_in[14];
    const float* b_cls = (const float*)d_in[15];
    const float* w_mean= (const float*)d_in[16];
    const float* b_mean= (const float*)d_in[17];
    float* out = (float*)d_out;

    // ---- level tables ----
    Tab tab;
    const int Hs[5]  = {13, 25, 50, 100, 200};
    const int Ws5[5] = {19, 38, 76, 152, 304};
    int bsum = 0, psum = 0, csum = 0;
    for (int L = 0; L < 5; ++L) {
        tab.H[L] = Hs[L]; tab.W5[L] = Ws5[L];
        tab.tilesX[L] = (Ws5[L] + 15) / 16;
        tab.blkBase[L] = bsum;
        bsum += tab.tilesX[L] * ((Hs[L] + 7) / 8);
        tab.poff[L] = psum;
        tab.cvtBase[L] = csum;
        const int HW = Hs[L] * Ws5[L];
        psum += HW;
        csum += (HW + 63) / 64;
    }
    tab.blkBase[5] = bsum; tab.poff[5] = psum; tab.cvtBase[5] = csum;

    // ---- workspace layout (all 16B-aligned) ----
    const size_t BIGE = (size_t)2 * TOT * 256;   // 41,470,464 elems
    ushort* XBF  = (ushort*)d_ws;                // x NHWC; later aliased by H2
    ushort* H1   = XBF + BIGE;                   // h1 NHWC
    ushort* U    = H1 + BIGE;                    // U NHWC
    ushort* H2   = XBF;                          // h2 NHWC, aliases dead XN
    float*  MIXv = (float*)(U + BIGE);           // [b][TOT][4]
    float*  btabT= MIXv + (size_t)2 * TOT * 4;   // 9216
    float*  wcp  = btabT + 9216;                 // 512
    float*  wmp  = wcp + 512;                    // 1024
    ushort* PW1  = (ushort*)(wmp + 1024);
    ushort* PW2  = PW1 + 589824;
    ushort* PWR  = PW2 + 589824;
    ushort* PWQY = PWR + 589824;

    // ---- prep ----
    cvtT_kernel<<<dim3(csum, 1, 2), 256, 0, stream>>>(
        (const float*)d_in[0], (const float*)d_in[1], (const float*)d_in[2],
        (const float*)d_in[3], (const float*)d_in[4], XBF, tab);
    pack_w_kernel<<<2304, 256, 0, stream>>>(w_qy1, PW1, 256);
    pack_w_kernel<<<2304, 256, 0, stream>>>(w_qy2, PW2, 256);
    pack_w_kernel<<<2304, 256, 0, stream>>>(w_rpn, PWR, 260);
    pack_qy_kernel<<<36, 256, 0, stream>>>(w_qy, PWQY);
    btabT_kernel<<<9, 256, 0, stream>>>(w_rpn, btabT);
    pack_head_kernel<<<1, 256, 0, stream>>>(w_cls, w_mean, wcp, wmp);

    // ---- D1: conv1 (x->h1, relu) + convR (x->U) fused ----
    conv3x3_mfma<<<dim3(bsum, 2, 4), 256, 0, stream>>>(
        XBF, PW1, PWR, b_qy1, b_rpn, H1, U, /*jobs=*/2, /*reluFlags=*/0b01, tab);

    // ---- D2: conv2 (h1->h2, relu) ----
    conv3x3_mfma<<<dim3(bsum, 2, 2), 256, 0, stream>>>(
        H1, PW2, PW2, b_qy2, b_qy2, H2, H2, /*jobs=*/1, /*reluFlags=*/0b1, tab);

    // ---- D3: qy conv + softmax -> mix ----
    qy_softmax_kernel<<<dim3((TOT + 63) / 64, 1, 2), 256, 0, stream>>>(
        H2, PWQY, b_qy, MIXv, tab);

    // ---- D4: heads + mixture + decode + clip ----
    final_kernel<<<dim3((TOT + 63) / 64, 1, 2), 256, 0, stream>>>(
        MIXv, U, btabT, wcp, wmp, b_cls, b_mean, im_info, out, tab);
}

// Round 5
// 2323.984 us; speedup vs baseline: 5.5924x; 1.0020x over previous
//
#include <hip/hip_runtime.h>
#include <math.h>

// ---------------------------------------------------------------------------
// RPN GMM head, MI355X. Round 5: R4 + weight-locality fixes.
//  (a) grid linearized so the 4 (ocHalf x job) variants of a (tile,b) are
//      consecutive blocks -> input tile fetched once, hit 3x in L2.
//  (b) non-temporal stores for all big streams (conv epilogue, cvtT) so the
//      1.18MB/job packed weights stay L2-resident (they were being thrashed:
//      3.0 GB of weight gather requests, ~1.2 GB missing to HBM).
// conv3x3(concat[x, onehot_n], w_rpn) == conv3x3(x, w_rpn[:,:256]) + edge bias
// Conv = 9 tap-GEMMs, 128oc x (16x*8y)pos tile, mfma_f32_16x16x32_bf16.
// ---------------------------------------------------------------------------

typedef __attribute__((ext_vector_type(8))) short short8;
typedef __attribute__((ext_vector_type(4))) float f32x4;

#define TOT 80997

struct Tab {
    int tilesX[5];
    int blkBase[6];
    int H[5];
    int W5[5];
    int poff[6];
    int cvtBase[6];
};

static __device__ __forceinline__ ushort f2bf(float f) {
    union { float f; unsigned u; } x; x.f = f;
    unsigned r = (x.u + 0x7FFFu + ((x.u >> 16) & 1u)) >> 16;  // RNE
    return (ushort)r;
}
static __device__ __forceinline__ float bf2f(ushort u) {
    union { unsigned u; float f; } x; x.u = ((unsigned)u) << 16;
    return x.f;
}

// -------- NCHW fp32 -> NHWC bf16 transpose-convert (64-pos x 256-ic tiles) --
__global__ __launch_bounds__(256) void cvtT_kernel(
    const float* __restrict__ f0, const float* __restrict__ f1,
    const float* __restrict__ f2, const float* __restrict__ f3,
    const float* __restrict__ f4, ushort* __restrict__ xn, Tab tab)
{
    __shared__ __align__(16) ushort s[64 * 264];
    const int tid = threadIdx.x;
    int t = blockIdx.x, L = 0;
    while (t >= tab.cvtBase[L + 1]) ++L;
    const int tile = t - tab.cvtBase[L];
    const int HW = tab.H[L] * tab.W5[L];
    const int pos0 = tile * 64;
    const int b = blockIdx.z;
    const float* fs[5] = {f0, f1, f2, f3, f4};
    const float* xp = fs[L] + (size_t)b * 256 * HW;

    const int p = tid & 63;
    const int icr = tid >> 6;
    const int pos = pos0 + p;
    for (int ic4 = 0; ic4 < 256; ic4 += 4) {
        const int ic = ic4 + icr;
        float v = 0.f;
        if (pos < HW) v = xp[(size_t)ic * HW + pos];
        s[p * 264 + ic] = f2bf(v);
    }
    __syncthreads();
    const int seg = tid & 31;
    for (int k = 0; k < 8; ++k) {
        const int pp = (tid >> 5) + k * 8;
        const int gpos = pos0 + pp;
        if (gpos < HW) {
            short8 v = *(const short8*)&s[pp * 264 + seg * 8];
            __builtin_nontemporal_store(v,
                (short8*)(xn + ((size_t)b * TOT + tab.poff[L] + gpos) * 256 + seg * 8));
        }
    }
}

// -------- weight pack: w[oc][ic][ky][kx] fp32 -> pw[tap][oc][ic] bf16 ------
__global__ __launch_bounds__(256) void pack_w_kernel(
    const float* __restrict__ w, ushort* __restrict__ pw, int icfull)
{
    int idx = blockIdx.x * 256 + threadIdx.x;
    if (idx >= 589824) return;
    int ic  = idx & 255;
    int oc  = (idx >> 8) & 255;
    int tap = idx >> 16;
    pw[idx] = f2bf(w[((size_t)oc * icfull + ic) * 9 + tap]);
}

// -------- qy weight pack: wqy[n][ic][tap] fp32 -> pwqy[n][tap][ic] bf16 ----
__global__ __launch_bounds__(256) void pack_qy_kernel(
    const float* __restrict__ wqy, ushort* __restrict__ pwqy)
{
    int idx = blockIdx.x * 256 + threadIdx.x;   // 4*9*256 = 9216
    if (idx >= 9216) return;
    int ic = idx & 255;
    int t  = (idx >> 8) % 9;
    int n  = (idx >> 8) / 9;
    pwqy[idx] = f2bf(wqy[n * 2304 + ic * 9 + t]);
}

// ---- edge-bias table, transposed: btabT[case][oc][n] (float4 per oc) ------
__global__ __launch_bounds__(256) void btabT_kernel(
    const float* __restrict__ w_rpn, float* __restrict__ btabT)
{
    int idx = blockIdx.x * 256 + threadIdx.x;   // 9*256
    if (idx >= 2304) return;
    const int oc = idx & 255;
    const int cs = idx >> 8;
    const int cy = cs / 3, cx = cs % 3;
    float4 o;
    float* op = (float*)&o;
    for (int n = 0; n < 4; ++n) {
        float s = 0.f;
        for (int ky = 0; ky < 3; ++ky) {
            if (cy == 0 && ky == 0) continue;
            if (cy == 2 && ky == 2) continue;
            for (int kx = 0; kx < 3; ++kx) {
                if (cx == 0 && kx == 0) continue;
                if (cx == 2 && kx == 2) continue;
                s += w_rpn[(size_t)oc * 2340 + (256 + n) * 9 + ky * 3 + kx];
            }
        }
        op[n] = s;
    }
    ((float4*)btabT)[cs * 256 + oc] = o;
}

// -------- head weight pack: wcp[oc]={cls0,cls1}, wmp[oc]={m0..m3} ----------
__global__ void pack_head_kernel(const float* __restrict__ w_cls,
                                 const float* __restrict__ w_mean,
                                 float* __restrict__ wcp, float* __restrict__ wmp)
{
    const int oc = threadIdx.x;  // 256
    wcp[oc * 2]     = w_cls[oc];
    wcp[oc * 2 + 1] = w_cls[256 + oc];
    float4 m;
    m.x = w_mean[oc];       m.y = w_mean[256 + oc];
    m.z = w_mean[512 + oc]; m.w = w_mean[768 + oc];
    ((float4*)wmp)[oc] = m;
}

// ------------------- big 3x3 conv: 256 -> 256, bf16 MFMA -------------------
// 1-D grid, linear id = ((tile*B + b)*jobs + job)*2 + ocHalf  ->  the 2*jobs
// variants of a (tile,b) are CONSECUTIVE blocks (input-tile L2 reuse).
// LDS: s_in [10 rows][8 icb][18 x][8 ic] unioned with s_out [128 pos][136 oc].
__global__ __launch_bounds__(256, 4) void conv3x3_mfma(
    const ushort* __restrict__ inN,   // NHWC bf16 [b][TOT][256]
    const ushort* __restrict__ pw0, const ushort* __restrict__ pw1,
    const float* __restrict__ bias0, const float* __restrict__ bias1,
    ushort* __restrict__ out0, ushort* __restrict__ out1,
    int jobs, int reluFlags, Tab tab)
{
    __shared__ __align__(16) char smem[34816];
    ushort* s_in  = (ushort*)smem;   // [10][8][18][8]
    ushort* s_out = (ushort*)smem;   // [128][136]

    const int tid = threadIdx.x;
    // ---- linear block decode: ocHalf fastest, then job, then b, then tile --
    int id = blockIdx.x;
    const int ocHalf = id & 1;
    int rest = id >> 1;
    const int job = rest % jobs;  rest /= jobs;
    const int b   = rest & 1;
    int t = rest >> 1;
    int L = 0;
    while (t >= tab.blkBase[L + 1]) ++L;
    const int rel = t - tab.blkBase[L];
    const int tX = tab.tilesX[L];
    const int H = tab.H[L], W = tab.W5[L];
    const int y0 = (rel / tX) * 8;
    const int x0 = (rel % tX) * 16;
    const int oc0 = ocHalf * 128;
    const ushort* pw   = job ? pw1 : pw0;
    const float*  bias = job ? bias1 : bias0;
    ushort*       out  = job ? out1 : out0;
    const int relu = (reluFlags >> job) & 1;
    const size_t posB = (size_t)b * TOT + tab.poff[L];

    const int lane = tid & 63;
    const int wave = tid >> 6;
    const int lm   = lane & 15;
    const int quad = lane >> 4;
    const int wrow = wave >> 1;   // oc half within 128
    const int wcol = wave & 1;    // y quad

    f32x4 acc[4][4];
#pragma unroll
    for (int i = 0; i < 4; ++i)
#pragma unroll
        for (int j = 0; j < 4; ++j) acc[i][j] = (f32x4){0.f, 0.f, 0.f, 0.f};

    const ushort* pwl = pw + (size_t)(oc0 + wrow * 64 + lm) * 256 + quad * 8;
    const int siteT = tid >> 3;   // 8 lanes per site
    const int icg   = tid & 7;

#pragma unroll 1
    for (int ic0i = 0; ic0i < 256; ic0i += 64) {
        __syncthreads();
        // stage: 180 sites (10 rows x 18 x); site's 64 ic = 128 B contiguous
        for (int s0 = 0; s0 < 180; s0 += 32) {
            const int site = s0 + siteT;
            if (site < 180) {
                const int r  = site / 18;
                const int xx = site - r * 18;
                const int yi = y0 - 1 + r, xi = x0 - 1 + xx;
                short8 v = {0, 0, 0, 0, 0, 0, 0, 0};
                if (yi >= 0 && yi < H && xi >= 0 && xi < W)
                    v = *(const short8*)(inN + (posB + (size_t)yi * W + xi) * 256
                                         + ic0i + icg * 8);
                *(short8*)&s_in[((r * 8 + icg) * 18 + xx) * 8] = v;
            }
        }
        __syncthreads();

#pragma unroll
        for (int sub = 0; sub < 2; ++sub) {
            const int icb = quad + sub * 4;
#pragma unroll
            for (int kx = 0; kx < 3; ++kx) {
                short8 bv[6];   // halo rows wcol*4 .. wcol*4+5
#pragma unroll
                for (int r = 0; r < 6; ++r)
                    bv[r] = *(const short8*)
                        &s_in[(((wcol * 4 + r) * 8 + icb) * 18 + lm + kx) * 8];
#pragma unroll
                for (int ky = 0; ky < 3; ++ky) {
                    const ushort* pa = pwl + (ky * 3 + kx) * 65536 + ic0i + sub * 32;
                    short8 av[4];
#pragma unroll
                    for (int i = 0; i < 4; ++i) av[i] = *(const short8*)(pa + i * 4096);
#pragma unroll
                    for (int i = 0; i < 4; ++i)
#pragma unroll
                        for (int j = 0; j < 4; ++j)
                            acc[i][j] = __builtin_amdgcn_mfma_f32_16x16x32_bf16(
                                av[i], bv[j + ky], acc[i][j], 0, 0, 0);
                }
            }
        }
    }

    __syncthreads();   // all MFMA LDS reads done before s_out overwrites s_in

    // bias + relu + cvt into s_out[pos 128][oc 136-padded]
#pragma unroll
    for (int i = 0; i < 4; ++i) {
        const int ocl = wrow * 64 + i * 16 + quad * 4;   // oc within 128
        const float4 bv4 = *(const float4*)(bias + oc0 + ocl);
#pragma unroll
        for (int j = 0; j < 4; ++j) {
            const int posL = (wcol * 4 + j) * 16 + lm;
            float v0 = acc[i][j][0] + bv4.x;
            float v1 = acc[i][j][1] + bv4.y;
            float v2 = acc[i][j][2] + bv4.z;
            float v3 = acc[i][j][3] + bv4.w;
            if (relu) {
                v0 = fmaxf(v0, 0.f); v1 = fmaxf(v1, 0.f);
                v2 = fmaxf(v2, 0.f); v3 = fmaxf(v3, 0.f);
            }
            ushort4 o;
            o.x = f2bf(v0); o.y = f2bf(v1); o.z = f2bf(v2); o.w = f2bf(v3);
            *(ushort4*)&s_out[posL * 136 + ocl] = o;
        }
    }
    __syncthreads();

    // coalesced non-temporal store: per position 128 oc = 256 B contiguous
#pragma unroll
    for (int it = 0; it < 8; ++it) {
        const int idx = it * 256 + tid;
        const int p   = idx >> 4;
        const int sgm = idx & 15;
        const int y = y0 + (p >> 4), x = x0 + (p & 15);
        if (y < H && x < W) {
            short8 v = *(const short8*)&s_out[p * 136 + sgm * 8];
            __builtin_nontemporal_store(v,
                (short8*)(out + (posB + (size_t)y * W + x) * 256 + oc0 + sgm * 8));
        }
    }
}

// ------- qy conv (256->4, 3x3) + softmax; NHWC h2; 4 lanes per position ----
__global__ __launch_bounds__(256) void qy_softmax_kernel(
    const ushort* __restrict__ h2, const ushort* __restrict__ pwqy, // [4][9][256]
    const float* __restrict__ bqy, float* __restrict__ mixv, Tab tab)
{
    const int tid = threadIdx.x;
    const int p = blockIdx.x * 64 + (tid >> 2);
    if (p >= TOT) return;
    const int q = tid & 3;
    const int b = blockIdx.z;
    int L = 0; while (p >= tab.poff[L + 1]) ++L;
    const int pos = p - tab.poff[L];
    const int W = tab.W5[L], H = tab.H[L];
    const int y = pos / W, x = pos - y * W;

    int  off[9];
    bool val[9];
#pragma unroll
    for (int ky = 0; ky < 3; ++ky)
#pragma unroll
        for (int kx = 0; kx < 3; ++kx) {
            const int t = ky * 3 + kx;
            const int yi = y + ky - 1, xi = x + kx - 1;
            val[t] = (yi >= 0 && yi < H && xi >= 0 && xi < W);
            off[t] = ((ky - 1) * W + (kx - 1)) * 256;
        }

    float a0 = 0.f, a1 = 0.f, a2 = 0.f, a3 = 0.f;
    const ushort* hp = h2 + ((size_t)b * TOT + p) * 256;
#pragma unroll 1
    for (int k = 0; k < 8; ++k) {
        const int sb = (k * 4 + q) * 8;
#pragma unroll
        for (int t = 0; t < 9; ++t) {
            if (!val[t]) continue;
            const short8 h8 = *(const short8*)(hp + off[t] + sb);
            float hv[8];
#pragma unroll
            for (int e = 0; e < 8; ++e) hv[e] = bf2f((ushort)h8[e]);
            const short8 w0 = *(const short8*)(pwqy + (0 * 9 + t) * 256 + sb);
            const short8 w1 = *(const short8*)(pwqy + (1 * 9 + t) * 256 + sb);
            const short8 w2 = *(const short8*)(pwqy + (2 * 9 + t) * 256 + sb);
            const short8 w3 = *(const short8*)(pwqy + (3 * 9 + t) * 256 + sb);
#pragma unroll
            for (int e = 0; e < 8; ++e) {
                a0 = fmaf(bf2f((ushort)w0[e]), hv[e], a0);
                a1 = fmaf(bf2f((ushort)w1[e]), hv[e], a1);
                a2 = fmaf(bf2f((ushort)w2[e]), hv[e], a2);
                a3 = fmaf(bf2f((ushort)w3[e]), hv[e], a3);
            }
        }
    }
    a0 += __shfl_xor(a0, 1); a0 += __shfl_xor(a0, 2);
    a1 += __shfl_xor(a1, 1); a1 += __shfl_xor(a1, 2);
    a2 += __shfl_xor(a2, 1); a2 += __shfl_xor(a2, 2);
    a3 += __shfl_xor(a3, 1); a3 += __shfl_xor(a3, 2);
    if (q == 0) {
        a0 += bqy[0]; a1 += bqy[1]; a2 += bqy[2]; a3 += bqy[3];
        const float mx = fmaxf(fmaxf(a0, a1), fmaxf(a2, a3));
        const float e0 = expf(a0 - mx), e1 = expf(a1 - mx);
        const float e2 = expf(a2 - mx), e3 = expf(a3 - mx);
        const float s = 1.f / (e0 + e1 + e2 + e3);
        float4 o; o.x = e0 * s; o.y = e1 * s; o.z = e2 * s; o.w = e3 * s;
        ((float4*)mixv)[(size_t)b * TOT + p] = o;
    }
}

// ------ final: T = sum_n mix_n*relu(u+bias_n); 6 heads; decode; clip -------
__global__ __launch_bounds__(256) void final_kernel(
    const float* __restrict__ mixv, const ushort* __restrict__ U,
    const float* __restrict__ btabT,
    const float* __restrict__ wcp, const float* __restrict__ wmp,
    const float* __restrict__ b_cls, const float* __restrict__ b_mean,
    const float* __restrict__ im_info,
    float* __restrict__ outp, Tab tab)
{
    const int tid = threadIdx.x;
    const int p = blockIdx.x * 64 + (tid >> 2);
    if (p >= TOT) return;
    const int q = tid & 3;
    const int b = blockIdx.z;
    int L = 0; while (p >= tab.poff[L + 1]) ++L;
    const int pos = p - tab.poff[L];
    const int W = tab.W5[L], H = tab.H[L];
    const int y = pos / W, x = pos - y * W;
    const int cy = (y == 0) ? 0 : ((y == H - 1) ? 2 : 1);
    const int cx = (x == 0) ? 0 : ((x == W - 1) ? 2 : 1);
    const float* bT = btabT + (size_t)(cy * 3 + cx) * 1024;

    const float4 mm = ((const float4*)mixv)[(size_t)b * TOT + p];
    const ushort* up = U + ((size_t)b * TOT + p) * 256;

    float sc0 = 0.f, sc1 = 0.f, D0 = 0.f, D1 = 0.f, D2 = 0.f, D3 = 0.f;
#pragma unroll 1
    for (int k = 0; k < 8; ++k) {
        const int seg = k * 4 + q;
        const short8 u8 = *(const short8*)(up + seg * 8);
#pragma unroll
        for (int e = 0; e < 8; ++e) {
            const int oc = seg * 8 + e;
            const float u = bf2f((ushort)u8[e]);
            const float4 bt = *(const float4*)(bT + oc * 4);
            float T =      mm.x * fmaxf(u + bt.x, 0.f);
            T = fmaf(mm.y, fmaxf(u + bt.y, 0.f), T);
            T = fmaf(mm.z, fmaxf(u + bt.z, 0.f), T);
            T = fmaf(mm.w, fmaxf(u + bt.w, 0.f), T);
            const float2 wc = *(const float2*)(wcp + oc * 2);
            const float4 wm = *(const float4*)(wmp + oc * 4);
            sc0 = fmaf(wc.x, T, sc0); sc1 = fmaf(wc.y, T, sc1);
            D0 = fmaf(wm.x, T, D0);   D1 = fmaf(wm.y, T, D1);
            D2 = fmaf(wm.z, T, D2);   D3 = fmaf(wm.w, T, D3);
        }
    }
    sc0 += __shfl_xor(sc0, 1); sc0 += __shfl_xor(sc0, 2);
    sc1 += __shfl_xor(sc1, 1); sc1 += __shfl_xor(sc1, 2);
    D0  += __shfl_xor(D0, 1);  D0  += __shfl_xor(D0, 2);
    D1  += __shfl_xor(D1, 1);  D1  += __shfl_xor(D1, 2);
    D2  += __shfl_xor(D2, 1);  D2  += __shfl_xor(D2, 2);
    D3  += __shfl_xor(D3, 1);  D3  += __shfl_xor(D3, 2);

    if (q == 0) {
        sc0 += b_cls[0]; sc1 += b_cls[1];
        D0 += b_mean[0]; D1 += b_mean[1]; D2 += b_mean[2]; D3 += b_mean[3];
        const float stride_ = (float)(64 >> L);
        const float aw  = stride_ * 8.f;
        const float acx = (x + 0.5f) * stride_;
        const float acy = (y + 0.5f) * stride_;
        const float cxx = acx + D0 * aw;
        const float cyy = acy + D1 * aw;
        const float e2 = fminf(fmaxf(D2, -10.f), 10.f);
        const float e3 = fminf(fmaxf(D3, -10.f), 10.f);
        const float bw = aw * expf(e2);
        const float bh = aw * expf(e3);
        const float imH = im_info[b * 6 + 0], imW = im_info[b * 6 + 1];
        const float x1 = fminf(fmaxf(cxx - 0.5f * bw, 0.f), imW);
        const float y1 = fminf(fmaxf(cyy - 0.5f * bh, 0.f), imH);
        const float x2 = fminf(fmaxf(cxx + 0.5f * bw, 0.f), imW);
        const float y2 = fminf(fmaxf(cyy + 0.5f * bh, 0.f), imH);
        float* op = outp + ((size_t)b * TOT + p) * 6;
        float2 w01; w01.x = x1; w01.y = y1;
        float2 w23; w23.x = x2; w23.y = y2;
        float2 w45; w45.x = sc0; w45.y = sc1;
        ((float2*)op)[0] = w01; ((float2*)op)[1] = w23; ((float2*)op)[2] = w45;
    }
}

// ---------------------------------------------------------------------------
extern "C" void kernel_launch(void* const* d_in, const int* in_sizes, int n_in,
                              void* d_out, int out_size, void* d_ws, size_t ws_size,
                              hipStream_t stream)
{
    (void)in_sizes; (void)n_in; (void)out_size; (void)ws_size;

    const float* im_info = (const float*)d_in[5];
    const float* w_qy1 = (const float*)d_in[6];
    const float* b_qy1 = (const float*)d_in[7];
    const float* w_qy2 = (const float*)d_in[8];
    const float* b_qy2 = (const float*)d_in[9];
    const float* w_qy  = (const float*)d_in[10];
    const float* b_qy  = (const float*)d_in[11];
    const float* w_rpn = (const float*)d_in[12];
    const float* b_rpn = (const float*)d_in[13];
    const float* w_cls = (const float*)d_in[14];
    const float* b_cls = (const float*)d_in[15];
    const float* w_mean= (const float*)d_in[16];
    const float* b_mean= (const float*)d_in[17];
    float* out = (float*)d_out;

    // ---- level tables ----
    Tab tab;
    const int Hs[5]  = {13, 25, 50, 100, 200};
    const int Ws5[5] = {19, 38, 76, 152, 304};
    int bsum = 0, psum = 0, csum = 0;
    for (int L = 0; L < 5; ++L) {
        tab.H[L] = Hs[L]; tab.W5[L] = Ws5[L];
        tab.tilesX[L] = (Ws5[L] + 15) / 16;
        tab.blkBase[L] = bsum;
        bsum += tab.tilesX[L] * ((Hs[L] + 7) / 8);
        tab.poff[L] = psum;
        tab.cvtBase[L] = csum;
        const int HW = Hs[L] * Ws5[L];
        psum += HW;
        csum += (HW + 63) / 64;
    }
    tab.blkBase[5] = bsum; tab.poff[5] = psum; tab.cvtBase[5] = csum;

    // ---- workspace layout (all 16B-aligned) ----
    const size_t BIGE = (size_t)2 * TOT * 256;   // 41,470,464 elems
    ushort* XBF  = (ushort*)d_ws;                // x NHWC; later aliased by H2
    ushort* H1   = XBF + BIGE;                   // h1 NHWC
    ushort* U    = H1 + BIGE;                    // U NHWC
    ushort* H2   = XBF;                          // h2 NHWC, aliases dead XN
    float*  MIXv = (float*)(U + BIGE);           // [b][TOT][4]
    float*  btabT= MIXv + (size_t)2 * TOT * 4;   // 9216
    float*  wcp  = btabT + 9216;                 // 512
    float*  wmp  = wcp + 512;                    // 1024
    ushort* PW1  = (ushort*)(wmp + 1024);
    ushort* PW2  = PW1 + 589824;
    ushort* PWR  = PW2 + 589824;
    ushort* PWQY = PWR + 589824;

    // ---- prep ----
    cvtT_kernel<<<dim3(csum, 1, 2), 256, 0, stream>>>(
        (const float*)d_in[0], (const float*)d_in[1], (const float*)d_in[2],
        (const float*)d_in[3], (const float*)d_in[4], XBF, tab);
    pack_w_kernel<<<2304, 256, 0, stream>>>(w_qy1, PW1, 256);
    pack_w_kernel<<<2304, 256, 0, stream>>>(w_qy2, PW2, 256);
    pack_w_kernel<<<2304, 256, 0, stream>>>(w_rpn, PWR, 260);
    pack_qy_kernel<<<36, 256, 0, stream>>>(w_qy, PWQY);
    btabT_kernel<<<9, 256, 0, stream>>>(w_rpn, btabT);
    pack_head_kernel<<<1, 256, 0, stream>>>(w_cls, w_mean, wcp, wmp);

    // ---- D1: conv1 (x->h1, relu) + convR (x->U) fused; linear grid,
    //      variants (ocHalf,job) consecutive per (tile,b) ----
    conv3x3_mfma<<<dim3(bsum * 2 * 2 * 2, 1, 1), 256, 0, stream>>>(
        XBF, PW1, PWR, b_qy1, b_rpn, H1, U, /*jobs=*/2, /*reluFlags=*/0b01, tab);

    // ---- D2: conv2 (h1->h2, relu) ----
    conv3x3_mfma<<<dim3(bsum * 2 * 2, 1, 1), 256, 0, stream>>>(
        H1, PW2, PW2, b_qy2, b_qy2, H2, H2, /*jobs=*/1, /*reluFlags=*/0b1, tab);

    // ---- D3: qy conv + softmax -> mix ----
    qy_softmax_kernel<<<dim3((TOT + 63) / 64, 1, 2), 256, 0, stream>>>(
        H2, PWQY, b_qy, MIXv, tab);

    // ---- D4: heads + mixture + decode + clip ----
    final_kernel<<<dim3((TOT + 63) / 64, 1, 2), 256, 0, stream>>>(
        MIXv, U, btabT, wcp, wmp, b_cls, b_mean, im_info, out, tab);
}

// Round 6
// 2208.692 us; speedup vs baseline: 5.8843x; 1.0522x over previous
//
#include <hip/hip_runtime.h>
#include <math.h>

// ---------------------------------------------------------------------------
// RPN GMM head, MI355X. Round 6: batch-pair conv tiles — each block computes
// its (tile, ocHalf, job) for BOTH batch images, so the 576KB of packed
// weights per block is amortized over 2x the MFMA work (weight L2-miss
// volume halves; rounds 3-5 showed dur ~= hbm_bytes / 2.05 TB/s).
// conv3x3(concat[x, onehot_n], w_rpn) == conv3x3(x, w_rpn[:,:256]) + edge bias
// Conv = 9 tap-GEMMs, 128oc x (16x*8y)pos x 2batch, mfma_f32_16x16x32_bf16.
// ---------------------------------------------------------------------------

typedef __attribute__((ext_vector_type(8))) short short8;
typedef __attribute__((ext_vector_type(4))) float f32x4;

#define TOT 80997

struct Tab {
    int tilesX[5];
    int blkBase[6];
    int H[5];
    int W5[5];
    int poff[6];
    int cvtBase[6];
};

static __device__ __forceinline__ ushort f2bf(float f) {
    union { float f; unsigned u; } x; x.f = f;
    unsigned r = (x.u + 0x7FFFu + ((x.u >> 16) & 1u)) >> 16;  // RNE
    return (ushort)r;
}
static __device__ __forceinline__ float bf2f(ushort u) {
    union { unsigned u; float f; } x; x.u = ((unsigned)u) << 16;
    return x.f;
}

// -------- NCHW fp32 -> NHWC bf16 transpose-convert (64-pos x 256-ic tiles) --
__global__ __launch_bounds__(256) void cvtT_kernel(
    const float* __restrict__ f0, const float* __restrict__ f1,
    const float* __restrict__ f2, const float* __restrict__ f3,
    const float* __restrict__ f4, ushort* __restrict__ xn, Tab tab)
{
    __shared__ __align__(16) ushort s[64 * 264];
    const int tid = threadIdx.x;
    int t = blockIdx.x, L = 0;
    while (t >= tab.cvtBase[L + 1]) ++L;
    const int tile = t - tab.cvtBase[L];
    const int HW = tab.H[L] * tab.W5[L];
    const int pos0 = tile * 64;
    const int b = blockIdx.z;
    const float* fs[5] = {f0, f1, f2, f3, f4};
    const float* xp = fs[L] + (size_t)b * 256 * HW;

    const int p = tid & 63;
    const int icr = tid >> 6;
    const int pos = pos0 + p;
    for (int ic4 = 0; ic4 < 256; ic4 += 4) {
        const int ic = ic4 + icr;
        float v = 0.f;
        if (pos < HW) v = xp[(size_t)ic * HW + pos];
        s[p * 264 + ic] = f2bf(v);
    }
    __syncthreads();
    const int seg = tid & 31;
    for (int k = 0; k < 8; ++k) {
        const int pp = (tid >> 5) + k * 8;
        const int gpos = pos0 + pp;
        if (gpos < HW) {
            short8 v = *(const short8*)&s[pp * 264 + seg * 8];
            __builtin_nontemporal_store(v,
                (short8*)(xn + ((size_t)b * TOT + tab.poff[L] + gpos) * 256 + seg * 8));
        }
    }
}

// -------- weight pack: w[oc][ic][ky][kx] fp32 -> pw[tap][oc][ic] bf16 ------
__global__ __launch_bounds__(256) void pack_w_kernel(
    const float* __restrict__ w, ushort* __restrict__ pw, int icfull)
{
    int idx = blockIdx.x * 256 + threadIdx.x;
    if (idx >= 589824) return;
    int ic  = idx & 255;
    int oc  = (idx >> 8) & 255;
    int tap = idx >> 16;
    pw[idx] = f2bf(w[((size_t)oc * icfull + ic) * 9 + tap]);
}

// -------- qy weight pack: wqy[n][ic][tap] fp32 -> pwqy[n][tap][ic] bf16 ----
__global__ __launch_bounds__(256) void pack_qy_kernel(
    const float* __restrict__ wqy, ushort* __restrict__ pwqy)
{
    int idx = blockIdx.x * 256 + threadIdx.x;   // 4*9*256 = 9216
    if (idx >= 9216) return;
    int ic = idx & 255;
    int t  = (idx >> 8) % 9;
    int n  = (idx >> 8) / 9;
    pwqy[idx] = f2bf(wqy[n * 2304 + ic * 9 + t]);
}

// ---- edge-bias table, transposed: btabT[case][oc][n] (float4 per oc) ------
__global__ __launch_bounds__(256) void btabT_kernel(
    const float* __restrict__ w_rpn, float* __restrict__ btabT)
{
    int idx = blockIdx.x * 256 + threadIdx.x;   // 9*256
    if (idx >= 2304) return;
    const int oc = idx & 255;
    const int cs = idx >> 8;
    const int cy = cs / 3, cx = cs % 3;
    float4 o;
    float* op = (float*)&o;
    for (int n = 0; n < 4; ++n) {
        float s = 0.f;
        for (int ky = 0; ky < 3; ++ky) {
            if (cy == 0 && ky == 0) continue;
            if (cy == 2 && ky == 2) continue;
            for (int kx = 0; kx < 3; ++kx) {
                if (cx == 0 && kx == 0) continue;
                if (cx == 2 && kx == 2) continue;
                s += w_rpn[(size_t)oc * 2340 + (256 + n) * 9 + ky * 3 + kx];
            }
        }
        op[n] = s;
    }
    ((float4*)btabT)[cs * 256 + oc] = o;
}

// -------- head weight pack: wcp[oc]={cls0,cls1}, wmp[oc]={m0..m3} ----------
__global__ void pack_head_kernel(const float* __restrict__ w_cls,
                                 const float* __restrict__ w_mean,
                                 float* __restrict__ wcp, float* __restrict__ wmp)
{
    const int oc = threadIdx.x;  // 256
    wcp[oc * 2]     = w_cls[oc];
    wcp[oc * 2 + 1] = w_cls[256 + oc];
    float4 m;
    m.x = w_mean[oc];       m.y = w_mean[256 + oc];
    m.z = w_mean[512 + oc]; m.w = w_mean[768 + oc];
    ((float4*)wmp)[oc] = m;
}

// ------------------- big 3x3 conv: 256 -> 256, bf16 MFMA -------------------
// Each block: one spatial tile (16x * 8y), one 128-oc half, one job, BOTH
// batches. Linear grid id = (tile*jobs + job)*2 + ocHalf.
// LDS: s_in [2 b][10 rows][8 icb][18 x][8 ic] (46KB), s_out union [128][136].
__global__ __launch_bounds__(256, 2) void conv3x3_mfma(
    const ushort* __restrict__ inN,   // NHWC bf16 [b][TOT][256]
    const ushort* __restrict__ pw0, const ushort* __restrict__ pw1,
    const float* __restrict__ bias0, const float* __restrict__ bias1,
    ushort* __restrict__ out0, ushort* __restrict__ out1,
    int jobs, int reluFlags, Tab tab)
{
    __shared__ __align__(16) ushort smem[2 * 11520];  // 46,080 B
    ushort* s_in  = smem;            // [bb][10][8][18][8]
    ushort* s_out = smem;            // [128][136] (epilogue reuse)

    const int tid = threadIdx.x;
    int id = blockIdx.x;
    const int ocHalf = id & 1;  id >>= 1;
    const int job = id % jobs;
    int t = id / jobs;
    int L = 0;
    while (t >= tab.blkBase[L + 1]) ++L;
    const int rel = t - tab.blkBase[L];
    const int tX = tab.tilesX[L];
    const int H = tab.H[L], W = tab.W5[L];
    const int y0 = (rel / tX) * 8;
    const int x0 = (rel % tX) * 16;
    const int oc0 = ocHalf * 128;
    const ushort* pw   = job ? pw1 : pw0;
    const float*  bias = job ? bias1 : bias0;
    ushort*       out  = job ? out1 : out0;
    const int relu = (reluFlags >> job) & 1;
    const int poff = tab.poff[L];

    const int lane = tid & 63;
    const int wave = tid >> 6;
    const int lm   = lane & 15;
    const int quad = lane >> 4;
    const int wrow = wave >> 1;   // oc half within 128
    const int wcol = wave & 1;    // y quad

    f32x4 acc[2][4][4];
#pragma unroll
    for (int bb = 0; bb < 2; ++bb)
#pragma unroll
        for (int i = 0; i < 4; ++i)
#pragma unroll
            for (int j = 0; j < 4; ++j)
                acc[bb][i][j] = (f32x4){0.f, 0.f, 0.f, 0.f};

    const ushort* pwl = pw + (size_t)(oc0 + wrow * 64 + lm) * 256 + quad * 8;
    const int siteT = tid >> 3;   // 8 lanes per site
    const int icg   = tid & 7;

#pragma unroll 1
    for (int ic0i = 0; ic0i < 256; ic0i += 64) {
        __syncthreads();
        // stage both batches: 360 sites (2b x 10 rows x 18 x), 128B each
        for (int s0 = 0; s0 < 360; s0 += 32) {
            const int site = s0 + siteT;
            if (site < 360) {
                const int bb = site >= 180;
                const int s2 = site - 180 * bb;
                const int r  = s2 / 18;
                const int xx = s2 - r * 18;
                const int yi = y0 - 1 + r, xi = x0 - 1 + xx;
                short8 v = {0, 0, 0, 0, 0, 0, 0, 0};
                if (yi >= 0 && yi < H && xi >= 0 && xi < W)
                    v = *(const short8*)(inN + ((size_t)bb * TOT + poff
                                         + (size_t)yi * W + xi) * 256
                                         + ic0i + icg * 8);
                *(short8*)&s_in[bb * 11520 + ((r * 8 + icg) * 18 + xx) * 8] = v;
            }
        }
        __syncthreads();

#pragma unroll
        for (int sub = 0; sub < 2; ++sub) {
            const int icb = quad + sub * 4;
#pragma unroll
            for (int kx = 0; kx < 3; ++kx) {
                short8 bv[2][6];   // halo rows wcol*4 .. wcol*4+5, both batches
#pragma unroll
                for (int bb = 0; bb < 2; ++bb)
#pragma unroll
                    for (int r = 0; r < 6; ++r)
                        bv[bb][r] = *(const short8*)
                            &s_in[bb * 11520
                                  + (((wcol * 4 + r) * 8 + icb) * 18 + lm + kx) * 8];
#pragma unroll
                for (int ky = 0; ky < 3; ++ky) {
                    const ushort* pa = pwl + (ky * 3 + kx) * 65536 + ic0i + sub * 32;
                    short8 av[4];
#pragma unroll
                    for (int i = 0; i < 4; ++i) av[i] = *(const short8*)(pa + i * 4096);
#pragma unroll
                    for (int bb = 0; bb < 2; ++bb)
#pragma unroll
                        for (int i = 0; i < 4; ++i)
#pragma unroll
                            for (int j = 0; j < 4; ++j)
                                acc[bb][i][j] = __builtin_amdgcn_mfma_f32_16x16x32_bf16(
                                    av[i], bv[bb][j + ky], acc[bb][i][j], 0, 0, 0);
                }
            }
        }
    }

    // ---- epilogue: two rounds (one per batch) through the LDS transpose ----
#pragma unroll 1
    for (int bb = 0; bb < 2; ++bb) {
        __syncthreads();   // prior-round LDS reads (or MFMA reads) complete
#pragma unroll
        for (int i = 0; i < 4; ++i) {
            const int ocl = wrow * 64 + i * 16 + quad * 4;   // oc within 128
            const float4 bv4 = *(const float4*)(bias + oc0 + ocl);
#pragma unroll
            for (int j = 0; j < 4; ++j) {
                const int posL = (wcol * 4 + j) * 16 + lm;
                float v0 = acc[bb][i][j][0] + bv4.x;
                float v1 = acc[bb][i][j][1] + bv4.y;
                float v2 = acc[bb][i][j][2] + bv4.z;
                float v3 = acc[bb][i][j][3] + bv4.w;
                if (relu) {
                    v0 = fmaxf(v0, 0.f); v1 = fmaxf(v1, 0.f);
                    v2 = fmaxf(v2, 0.f); v3 = fmaxf(v3, 0.f);
                }
                ushort4 o;
                o.x = f2bf(v0); o.y = f2bf(v1); o.z = f2bf(v2); o.w = f2bf(v3);
                *(ushort4*)&s_out[posL * 136 + ocl] = o;
            }
        }
        __syncthreads();
        // store: per position 128 oc = 256 B contiguous
#pragma unroll
        for (int it = 0; it < 8; ++it) {
            const int idx = it * 256 + tid;
            const int p   = idx >> 4;
            const int sgm = idx & 15;
            const int y = y0 + (p >> 4), x = x0 + (p & 15);
            if (y < H && x < W) {
                short8 v = *(const short8*)&s_out[p * 136 + sgm * 8];
                __builtin_nontemporal_store(v,
                    (short8*)(out + ((size_t)bb * TOT + poff + (size_t)y * W + x) * 256
                              + oc0 + sgm * 8));
            }
        }
    }
}

// ------- qy conv (256->4, 3x3) + softmax; NHWC h2; 4 lanes per position ----
__global__ __launch_bounds__(256) void qy_softmax_kernel(
    const ushort* __restrict__ h2, const ushort* __restrict__ pwqy, // [4][9][256]
    const float* __restrict__ bqy, float* __restrict__ mixv, Tab tab)
{
    const int tid = threadIdx.x;
    const int p = blockIdx.x * 64 + (tid >> 2);
    if (p >= TOT) return;
    const int q = tid & 3;
    const int b = blockIdx.z;
    int L = 0; while (p >= tab.poff[L + 1]) ++L;
    const int pos = p - tab.poff[L];
    const int W = tab.W5[L], H = tab.H[L];
    const int y = pos / W, x = pos - y * W;

    int  off[9];
    bool val[9];
#pragma unroll
    for (int ky = 0; ky < 3; ++ky)
#pragma unroll
        for (int kx = 0; kx < 3; ++kx) {
            const int t = ky * 3 + kx;
            const int yi = y + ky - 1, xi = x + kx - 1;
            val[t] = (yi >= 0 && yi < H && xi >= 0 && xi < W);
            off[t] = ((ky - 1) * W + (kx - 1)) * 256;
        }

    float a0 = 0.f, a1 = 0.f, a2 = 0.f, a3 = 0.f;
    const ushort* hp = h2 + ((size_t)b * TOT + p) * 256;
#pragma unroll 1
    for (int k = 0; k < 8; ++k) {
        const int sb = (k * 4 + q) * 8;
#pragma unroll
        for (int t = 0; t < 9; ++t) {
            if (!val[t]) continue;
            const short8 h8 = *(const short8*)(hp + off[t] + sb);
            float hv[8];
#pragma unroll
            for (int e = 0; e < 8; ++e) hv[e] = bf2f((ushort)h8[e]);
            const short8 w0 = *(const short8*)(pwqy + (0 * 9 + t) * 256 + sb);
            const short8 w1 = *(const short8*)(pwqy + (1 * 9 + t) * 256 + sb);
            const short8 w2 = *(const short8*)(pwqy + (2 * 9 + t) * 256 + sb);
            const short8 w3 = *(const short8*)(pwqy + (3 * 9 + t) * 256 + sb);
#pragma unroll
            for (int e = 0; e < 8; ++e) {
                a0 = fmaf(bf2f((ushort)w0[e]), hv[e], a0);
                a1 = fmaf(bf2f((ushort)w1[e]), hv[e], a1);
                a2 = fmaf(bf2f((ushort)w2[e]), hv[e], a2);
                a3 = fmaf(bf2f((ushort)w3[e]), hv[e], a3);
            }
        }
    }
    a0 += __shfl_xor(a0, 1); a0 += __shfl_xor(a0, 2);
    a1 += __shfl_xor(a1, 1); a1 += __shfl_xor(a1, 2);
    a2 += __shfl_xor(a2, 1); a2 += __shfl_xor(a2, 2);
    a3 += __shfl_xor(a3, 1); a3 += __shfl_xor(a3, 2);
    if (q == 0) {
        a0 += bqy[0]; a1 += bqy[1]; a2 += bqy[2]; a3 += bqy[3];
        const float mx = fmaxf(fmaxf(a0, a1), fmaxf(a2, a3));
        const float e0 = expf(a0 - mx), e1 = expf(a1 - mx);
        const float e2 = expf(a2 - mx), e3 = expf(a3 - mx);
        const float s = 1.f / (e0 + e1 + e2 + e3);
        float4 o; o.x = e0 * s; o.y = e1 * s; o.z = e2 * s; o.w = e3 * s;
        ((float4*)mixv)[(size_t)b * TOT + p] = o;
    }
}

// ------ final: T = sum_n mix_n*relu(u+bias_n); 6 heads; decode; clip -------
__global__ __launch_bounds__(256) void final_kernel(
    const float* __restrict__ mixv, const ushort* __restrict__ U,
    const float* __restrict__ btabT,
    const float* __restrict__ wcp, const float* __restrict__ wmp,
    const float* __restrict__ b_cls, const float* __restrict__ b_mean,
    const float* __restrict__ im_info,
    float* __restrict__ outp, Tab tab)
{
    const int tid = threadIdx.x;
    const int p = blockIdx.x * 64 + (tid >> 2);
    if (p >= TOT) return;
    const int q = tid & 3;
    const int b = blockIdx.z;
    int L = 0; while (p >= tab.poff[L + 1]) ++L;
    const int pos = p - tab.poff[L];
    const int W = tab.W5[L], H = tab.H[L];
    const int y = pos / W, x = pos - y * W;
    const int cy = (y == 0) ? 0 : ((y == H - 1) ? 2 : 1);
    const int cx = (x == 0) ? 0 : ((x == W - 1) ? 2 : 1);
    const float* bT = btabT + (size_t)(cy * 3 + cx) * 1024;

    const float4 mm = ((const float4*)mixv)[(size_t)b * TOT + p];
    const ushort* up = U + ((size_t)b * TOT + p) * 256;

    float sc0 = 0.f, sc1 = 0.f, D0 = 0.f, D1 = 0.f, D2 = 0.f, D3 = 0.f;
#pragma unroll 1
    for (int k = 0; k < 8; ++k) {
        const int seg = k * 4 + q;
        const short8 u8 = *(const short8*)(up + seg * 8);
#pragma unroll
        for (int e = 0; e < 8; ++e) {
            const int oc = seg * 8 + e;
            const float u = bf2f((ushort)u8[e]);
            const float4 bt = *(const float4*)(bT + oc * 4);
            float T =      mm.x * fmaxf(u + bt.x, 0.f);
            T = fmaf(mm.y, fmaxf(u + bt.y, 0.f), T);
            T = fmaf(mm.z, fmaxf(u + bt.z, 0.f), T);
            T = fmaf(mm.w, fmaxf(u + bt.w, 0.f), T);
            const float2 wc = *(const float2*)(wcp + oc * 2);
            const float4 wm = *(const float4*)(wmp + oc * 4);
            sc0 = fmaf(wc.x, T, sc0); sc1 = fmaf(wc.y, T, sc1);
            D0 = fmaf(wm.x, T, D0);   D1 = fmaf(wm.y, T, D1);
            D2 = fmaf(wm.z, T, D2);   D3 = fmaf(wm.w, T, D3);
        }
    }
    sc0 += __shfl_xor(sc0, 1); sc0 += __shfl_xor(sc0, 2);
    sc1 += __shfl_xor(sc1, 1); sc1 += __shfl_xor(sc1, 2);
    D0  += __shfl_xor(D0, 1);  D0  += __shfl_xor(D0, 2);
    D1  += __shfl_xor(D1, 1);  D1  += __shfl_xor(D1, 2);
    D2  += __shfl_xor(D2, 1);  D2  += __shfl_xor(D2, 2);
    D3  += __shfl_xor(D3, 1);  D3  += __shfl_xor(D3, 2);

    if (q == 0) {
        sc0 += b_cls[0]; sc1 += b_cls[1];
        D0 += b_mean[0]; D1 += b_mean[1]; D2 += b_mean[2]; D3 += b_mean[3];
        const float stride_ = (float)(64 >> L);
        const float aw  = stride_ * 8.f;
        const float acx = (x + 0.5f) * stride_;
        const float acy = (y + 0.5f) * stride_;
        const float cxx = acx + D0 * aw;
        const float cyy = acy + D1 * aw;
        const float e2 = fminf(fmaxf(D2, -10.f), 10.f);
        const float e3 = fminf(fmaxf(D3, -10.f), 10.f);
        const float bw = aw * expf(e2);
        const float bh = aw * expf(e3);
        const float imH = im_info[b * 6 + 0], imW = im_info[b * 6 + 1];
        const float x1 = fminf(fmaxf(cxx - 0.5f * bw, 0.f), imW);
        const float y1 = fminf(fmaxf(cyy - 0.5f * bh, 0.f), imH);
        const float x2 = fminf(fmaxf(cxx + 0.5f * bw, 0.f), imW);
        const float y2 = fminf(fmaxf(cyy + 0.5f * bh, 0.f), imH);
        float* op = outp + ((size_t)b * TOT + p) * 6;
        float2 w01; w01.x = x1; w01.y = y1;
        float2 w23; w23.x = x2; w23.y = y2;
        float2 w45; w45.x = sc0; w45.y = sc1;
        ((float2*)op)[0] = w01; ((float2*)op)[1] = w23; ((float2*)op)[2] = w45;
    }
}

// ---------------------------------------------------------------------------
extern "C" void kernel_launch(void* const* d_in, const int* in_sizes, int n_in,
                              void* d_out, int out_size, void* d_ws, size_t ws_size,
                              hipStream_t stream)
{
    (void)in_sizes; (void)n_in; (void)out_size; (void)ws_size;

    const float* im_info = (const float*)d_in[5];
    const float* w_qy1 = (const float*)d_in[6];
    const float* b_qy1 = (const float*)d_in[7];
    const float* w_qy2 = (const float*)d_in[8];
    const float* b_qy2 = (const float*)d_in[9];
    const float* w_qy  = (const float*)d_in[10];
    const float* b_qy  = (const float*)d_in[11];
    const float* w_rpn = (const float*)d_in[12];
    const float* b_rpn = (const float*)d_in[13];
    const float* w_cls = (const float*)d_in[14];
    const float* b_cls = (const float*)d_in[15];
    const float* w_mean= (const float*)d_in[16];
    const float* b_mean= (const float*)d_in[17];
    float* out = (float*)d_out;

    // ---- level tables ----
    Tab tab;
    const int Hs[5]  = {13, 25, 50, 100, 200};
    const int Ws5[5] = {19, 38, 76, 152, 304};
    int bsum = 0, psum = 0, csum = 0;
    for (int L = 0; L < 5; ++L) {
        tab.H[L] = Hs[L]; tab.W5[L] = Ws5[L];
        tab.tilesX[L] = (Ws5[L] + 15) / 16;
        tab.blkBase[L] = bsum;
        bsum += tab.tilesX[L] * ((Hs[L] + 7) / 8);
        tab.poff[L] = psum;
        tab.cvtBase[L] = csum;
        const int HW = Hs[L] * Ws5[L];
        psum += HW;
        csum += (HW + 63) / 64;
    }
    tab.blkBase[5] = bsum; tab.poff[5] = psum; tab.cvtBase[5] = csum;

    // ---- workspace layout (all 16B-aligned) ----
    const size_t BIGE = (size_t)2 * TOT * 256;   // 41,470,464 elems
    ushort* XBF  = (ushort*)d_ws;                // x NHWC; later aliased by H2
    ushort* H1   = XBF + BIGE;                   // h1 NHWC
    ushort* U    = H1 + BIGE;                    // U NHWC
    ushort* H2   = XBF;                          // h2 NHWC, aliases dead XN
    float*  MIXv = (float*)(U + BIGE);           // [b][TOT][4]
    float*  btabT= MIXv + (size_t)2 * TOT * 4;   // 9216
    float*  wcp  = btabT + 9216;                 // 512
    float*  wmp  = wcp + 512;                    // 1024
    ushort* PW1  = (ushort*)(wmp + 1024);
    ushort* PW2  = PW1 + 589824;
    ushort* PWR  = PW2 + 589824;
    ushort* PWQY = PWR + 589824;

    // ---- prep ----
    cvtT_kernel<<<dim3(csum, 1, 2), 256, 0, stream>>>(
        (const float*)d_in[0], (const float*)d_in[1], (const float*)d_in[2],
        (const float*)d_in[3], (const float*)d_in[4], XBF, tab);
    pack_w_kernel<<<2304, 256, 0, stream>>>(w_qy1, PW1, 256);
    pack_w_kernel<<<2304, 256, 0, stream>>>(w_qy2, PW2, 256);
    pack_w_kernel<<<2304, 256, 0, stream>>>(w_rpn, PWR, 260);
    pack_qy_kernel<<<36, 256, 0, stream>>>(w_qy, PWQY);
    btabT_kernel<<<9, 256, 0, stream>>>(w_rpn, btabT);
    pack_head_kernel<<<1, 256, 0, stream>>>(w_cls, w_mean, wcp, wmp);

    // ---- D1: conv1 (x->h1, relu) + convR (x->U), both batches per block ----
    conv3x3_mfma<<<dim3(bsum * 2 * 2, 1, 1), 256, 0, stream>>>(
        XBF, PW1, PWR, b_qy1, b_rpn, H1, U, /*jobs=*/2, /*reluFlags=*/0b01, tab);

    // ---- D2: conv2 (h1->h2, relu), both batches per block ----
    conv3x3_mfma<<<dim3(bsum * 2, 1, 1), 256, 0, stream>>>(
        H1, PW2, PW2, b_qy2, b_qy2, H2, H2, /*jobs=*/1, /*reluFlags=*/0b1, tab);

    // ---- D3: qy conv + softmax -> mix ----
    qy_softmax_kernel<<<dim3((TOT + 63) / 64, 1, 2), 256, 0, stream>>>(
        H2, PWQY, b_qy, MIXv, tab);

    // ---- D4: heads + mixture + decode + clip ----
    final_kernel<<<dim3((TOT + 63) / 64, 1, 2), 256, 0, stream>>>(
        MIXv, U, btabT, wcp, wmp, b_cls, b_mean, im_info, out, tab);
}